// Round 3
// baseline (685.889 us; speedup 1.0000x reference)
//
#include <hip/hip_runtime.h>

#define N_ 100000
#define D_ 128
#define O_ 128
#define V_ 3
#define E_ 400000
#define NB_SCAN 98   // ceil(N/1024)
#define EGRID 1563   // ceil(E/256)
#define MB 16        // nodes per k_fused block (one node per 16-lane group)
#define NBLK (N_ / MB)   // 6250
#define LDA 136      // padded bf16 row stride (16B-aligned)

// fused pre-kernel block ranges
#define PRE_CVT  6250                   // feature cvt (f32 path only)
#define PRE_PREW (PRE_CVT + 64)         // 6314
#define PRE_PREP (PRE_PREW + 617)       // 6931
#define PRE_TOT  (PRE_PREP + 3 * EGRID) // 11620

typedef unsigned short u16;
typedef __attribute__((ext_vector_type(8))) short bf16x8;   // 8 bf16 = 4 VGPRs
typedef __attribute__((ext_vector_type(4))) float f32x4;

#define MFMA16x16x32 __builtin_amdgcn_mfma_f32_16x16x32_bf16

// ---- fp32 param block offsets (in workspace, filled by prep) ----
#define P_RELB  0
#define P_GATEB 384
#define P_VP    768
#define P_VAB1  1152
#define P_VAW2  1216
#define P_VAB2  1280
#define P_LAB1  1281
#define P_LAW2  1409
#define P_LAB2  1537
#define P_PREDB 1539
#define P_ATTB  1541
#define P_FTB   1542
#define P_LNG   1670
#define P_LNB   1798
#define P_PREDW 1926
#define P_TOTAL 2182

__device__ __forceinline__ float b2f(u16 u) {
    union { float f; unsigned int i; } x; x.i = ((unsigned int)u) << 16; return x.f;
}
__device__ __forceinline__ float blo(unsigned int u) {
    union { float f; unsigned int i; } x; x.i = u << 16; return x.f;
}
__device__ __forceinline__ float bhi(unsigned int u) {
    union { float f; unsigned int i; } x; x.i = u & 0xffff0000u; return x.f;
}
__device__ __forceinline__ u16 f2b(float f) {
    union { float f; unsigned int i; } x; x.f = f;
    unsigned int r = x.i + 0x7FFFu + ((x.i >> 16) & 1u);
    return (u16)(r >> 16);
}

template<int F32> __device__ __forceinline__ float LD(const void* p, size_t i) {
    if (F32) return ((const float*)p)[i];
    return b2f(((const u16*)p)[i]);
}

// ---------------- dtype detector: fp32 vs bf16 element stream ----------------
__global__ void k_detect(const u16* __restrict__ feat, int* __restrict__ flag) {
    int t = threadIdx.x;   // 64 lanes; check feat[2i], i = t and t+64
    u16 a = feat[2 * t], b = feat[2 * t + 128];
    int zeros = (a == 0 ? 1 : 0) + (b == 0 ? 1 : 0);
    float va = b2f(a), vb = b2f(b);
    int bad = (!(va > -128.f && va < 128.f) ? 1 : 0) +
              (!(vb > -128.f && vb < 128.f) ? 1 : 0);
    #pragma unroll
    for (int s = 1; s <= 32; s <<= 1) {
        bad += __shfl_xor(bad, s);
        zeros += __shfl_xor(zeros, s);
    }
    if (t == 0) flag[0] = (bad >= 16 || zeros >= 64) ? 1 : 0;
}

// ---------------- fused pre kernel: cvt | prew | prep | count ----------------
__device__ __forceinline__ void cvt_body_f32(int b, const void* feat,
                                             u16* __restrict__ featB) {
    size_t idx = (size_t)b * 256 + threadIdx.x;   // 8 elems per thread
    const float4* fp = (const float4*)feat;
    float4 a = fp[idx * 2], c = fp[idx * 2 + 1];
    uint4 u;
    u.x = (unsigned)f2b(a.x) | ((unsigned)f2b(a.y) << 16);
    u.y = (unsigned)f2b(a.z) | ((unsigned)f2b(a.w) << 16);
    u.z = (unsigned)f2b(c.x) | ((unsigned)f2b(c.y) << 16);
    u.w = (unsigned)f2b(c.z) | ((unsigned)f2b(c.w) << 16);
    ((uint4*)featB)[idx] = u;
}

template<int F32>
__device__ __forceinline__ void prew_body(int b, const void* sl_w, const void* sl_b,
                                          const void* fus_w, const void* fus_b,
                                          u16* __restrict__ W1T, float* __restrict__ b1) {
    int gid = b * 256 + threadIdx.x;   // 64 blocks
    int d = gid >> 7, o = gid & 127;
    float acc = 0.f;
    for (int k = 0; k < 128; ++k)
        acc += LD<F32>(sl_w, d * 128 + k) * LD<F32>(fus_w, k * 128 + o);
    W1T[o * 128 + d] = f2b(acc);
    if (gid < 128) {
        float accb = 0.f;
        for (int k = 0; k < 128; ++k)
            accb += LD<F32>(sl_b, k) * LD<F32>(fus_w, k * 128 + gid);
        b1[gid] = accb + LD<F32>(fus_b, gid);
    }
}

template<int F32>
__device__ __forceinline__ void prep_body(int b,
        const void* rel_w, const void* gate_w, const void* va_w1, const void* fus_w,
        const void* ft_w, const void* la_w1,
        const void* rel_b, const void* gate_b, const void* vpref,
        const void* va_b1, const void* va_w2, const void* va_b2,
        const void* la_b1, const void* la_w2, const void* la_b2,
        const void* pred_b, const void* att_bias, const void* ft_b,
        const void* ln_g, const void* ln_beta, const void* pred_w,
        u16* __restrict__ relT, u16* __restrict__ gateT, u16* __restrict__ vaT,
        u16* __restrict__ fus2T, u16* __restrict__ ftT, u16* __restrict__ laT,
        float* __restrict__ P) {
    int id = b * 256 + threadIdx.x;
    if (id < 49152) {
        int v = id >> 14, r = id & 16383, o = r >> 7, d = r & 127;
        relT[id] = f2b(LD<F32>(rel_w, (size_t)v * 16384 + d * 128 + o));
    } else if (id < 98304) {
        int t = id - 49152, v = t >> 14, r = t & 16383, o = r >> 7, d = r & 127;
        gateT[t] = f2b(LD<F32>(gate_w, (size_t)v * 16384 + d * 128 + o));
    } else if (id < 106496) {
        int t = id - 98304, n = t >> 7, k = t & 127;
        vaT[t] = f2b(LD<F32>(va_w1, k * 64 + n));
    } else if (id < 122880) {
        int t = id - 106496, n = t >> 7, k = t & 127;
        fus2T[t] = f2b(LD<F32>(fus_w, (128 + k) * 128 + n));
    } else if (id < 139264) {
        int t = id - 122880, o = t >> 7, d = t & 127;
        ftT[t] = f2b(LD<F32>(ft_w, d * 128 + o));
    } else if (id < 155648) {
        int t = id - 139264, n = t >> 7, d = t & 127;
        int c = n >> 6, j = n & 63;
        laT[t] = f2b(LD<F32>(la_w1, c * 8192 + d * 64 + j));
    } else if (id < 155648 + P_TOTAL) {
        int t = id - 155648;
        float val;
        if      (t < P_GATEB) val = LD<F32>(rel_b, t);
        else if (t < P_VP)    val = LD<F32>(gate_b, t - P_GATEB);
        else if (t < P_VAB1)  val = LD<F32>(vpref, t - P_VP);
        else if (t < P_VAW2)  val = LD<F32>(va_b1, t - P_VAB1);
        else if (t < P_VAB2)  val = LD<F32>(va_w2, t - P_VAW2);
        else if (t < P_LAB1)  val = LD<F32>(va_b2, 0);
        else if (t < P_LAW2)  val = LD<F32>(la_b1, t - P_LAB1);
        else if (t < P_LAB2)  val = LD<F32>(la_w2, t - P_LAW2);
        else if (t < P_PREDB) val = LD<F32>(la_b2, t - P_LAB2);
        else if (t < P_ATTB)  val = LD<F32>(pred_b, t - P_PREDB);
        else if (t < P_FTB)   val = LD<F32>(att_bias, 0);
        else if (t < P_LNG)   val = LD<F32>(ft_b, t - P_FTB);
        else if (t < P_LNB)   val = LD<F32>(ln_g, t - P_LNG);
        else if (t < P_PREDW) val = LD<F32>(ln_beta, t - P_LNB);
        else                  val = LD<F32>(pred_w, t - P_PREDW);
        P[t] = val;
    }
}

__global__ __launch_bounds__(256) void k_preC(const int* __restrict__ flag,
        const void* feat, u16* __restrict__ featB,
        const void* sl_w, const void* sl_b, const void* fus_w, const void* fus_b,
        u16* __restrict__ W1T, float* __restrict__ b1,
        const void* rel_w, const void* gate_w, const void* va_w1,
        const void* ft_w, const void* la_w1,
        const void* rel_b, const void* gate_b, const void* vpref,
        const void* va_b1, const void* va_w2, const void* va_b2,
        const void* la_b1, const void* la_w2, const void* la_b2,
        const void* pred_b, const void* att_bias, const void* ft_b,
        const void* ln_g, const void* ln_beta, const void* pred_w,
        u16* __restrict__ relT, u16* __restrict__ gateT, u16* __restrict__ vaT,
        u16* __restrict__ fus2T, u16* __restrict__ ftT, u16* __restrict__ laT,
        float* __restrict__ P,
        const int* __restrict__ ei, int* __restrict__ cur3) {
    int b = blockIdx.x;
    if (b < PRE_CVT) {
        if (flag[0]) cvt_body_f32(b, feat, featB);   // bf16 case: featB unused
    } else if (b < PRE_PREW) {
        if (flag[0]) prew_body<1>(b - PRE_CVT, sl_w, sl_b, fus_w, fus_b, W1T, b1);
        else         prew_body<0>(b - PRE_CVT, sl_w, sl_b, fus_w, fus_b, W1T, b1);
    } else if (b < PRE_PREP) {
        if (flag[0]) prep_body<1>(b - PRE_PREW, rel_w, gate_w, va_w1, fus_w, ft_w, la_w1,
                                  rel_b, gate_b, vpref, va_b1, va_w2, va_b2,
                                  la_b1, la_w2, la_b2, pred_b, att_bias, ft_b,
                                  ln_g, ln_beta, pred_w, relT, gateT, vaT, fus2T, ftT, laT, P);
        else         prep_body<0>(b - PRE_PREW, rel_w, gate_w, va_w1, fus_w, ft_w, la_w1,
                                  rel_b, gate_b, vpref, va_b1, va_w2, va_b2,
                                  la_b1, la_w2, la_b2, pred_b, att_bias, ft_b,
                                  ln_g, ln_beta, pred_w, relT, gateT, vaT, fus2T, ftT, laT, P);
    } else {
        int b2 = b - PRE_PREP;
        int v = b2 / EGRID;
        int e = (b2 % EGRID) * 256 + threadIdx.x;
        if (e < E_) atomicAdd(&cur3[v * N_ + ei[(size_t)v * 2 * E_ + E_ + e]], 1);
    }
}

// ---------------- CSR scan: bsum / write (inline spine) ----------------------
__global__ __launch_bounds__(256) void k_scan_bsum(const int* __restrict__ cur3,
                                                   int* __restrict__ bsum) {
    __shared__ int red[256];
    const int v = blockIdx.x / NB_SCAN, b = blockIdx.x % NB_SCAN, tid = threadIdx.x;
    const int base = b * 1024;
    const int* counts = cur3 + v * N_;
    int s = 0;
    for (int i = tid; i < 1024; i += 256) {
        int idx = base + i;
        s += (idx < N_) ? counts[idx] : 0;
    }
    red[tid] = s;
    __syncthreads();
    for (int st = 128; st >= 1; st >>= 1) {
        if (tid < st) red[tid] += red[tid + st];
        __syncthreads();
    }
    if (tid == 0) bsum[v * 128 + b] = red[0];
}

__global__ __launch_bounds__(256) void k_scan_write(int* __restrict__ cur3,
                                                    const int* __restrict__ bsum,
                                                    int* __restrict__ offs3) {
    __shared__ int lsum[256];
    __shared__ int bs_s[128];
    const int v = blockIdx.x / NB_SCAN, b = blockIdx.x % NB_SCAN, tid = threadIdx.x;
    const int base = b * 1024;
    int* counts = cur3 + v * N_;
    int* offs   = offs3 + v * N_;
    if (tid < 128) bs_s[tid] = (tid < b) ? bsum[v * 128 + tid] : 0;
    int c[4]; int s = 0;
    #pragma unroll
    for (int k = 0; k < 4; ++k) {
        int idx = base + tid * 4 + k;
        c[k] = (idx < N_) ? counts[idx] : 0;
        s += c[k];
    }
    lsum[tid] = s;
    __syncthreads();
    for (int st = 1; st < 256; st <<= 1) {
        int t = (tid >= st) ? lsum[tid - st] : 0;
        __syncthreads();
        lsum[tid] += t;
        __syncthreads();
    }
    for (int st = 64; st >= 1; st >>= 1) {
        if (tid < st) bs_s[tid] += bs_s[tid + st];
        __syncthreads();
    }
    int off = bs_s[0] + lsum[tid] - s;
    #pragma unroll
    for (int k = 0; k < 4; ++k) {
        int idx = base + tid * 4 + k;
        if (idx < N_) { offs[idx] = off; counts[idx] = off; }
        off += c[k];
    }
}

// place: srcw[pos] = {src, weight-bits}
template<int F32>
__device__ __forceinline__ void place_body(const int* __restrict__ ei, const void* ew_all,
                                           int* __restrict__ cur3, int2* __restrict__ srcw3) {
    int v = blockIdx.x / EGRID;
    int e = (blockIdx.x % EGRID) * 256 + threadIdx.x;
    if (e < E_) {
        int dst = ei[(size_t)v * 2 * E_ + E_ + e];
        int src = ei[(size_t)v * 2 * E_ + e];
        float w = LD<F32>(ew_all, (size_t)v * E_ + e);
        int pos = atomicAdd(&cur3[v * N_ + dst], 1);
        int2 sw; sw.x = src; sw.y = __float_as_int(w);
        srcw3[(size_t)v * E_ + pos] = sw;
    }
    // afterwards cur3[v*N+n] == row end
}
__global__ __launch_bounds__(256) void k_place(const int* __restrict__ flag,
                                               const int* __restrict__ ei, const void* ew,
                                               int* __restrict__ cur3, int2* __restrict__ srcw3) {
    if (flag[0]) place_body<1>(ei, ew, cur3, srcw3);
    else         place_body<0>(ei, ew, cur3, srcw3);
}

// ------ fused MFMA pipeline: MB=16, one node per 16-lane group ---------------
// LDS ~18 KB, VGPR<=64 -> 8 blocks/CU (32 waves, 100% occupancy target).
__global__ __launch_bounds__(256, 8) void k_fused(const int* __restrict__ flag,
        const void* feat, const u16* __restrict__ featB_,
        const int2* __restrict__ srcw3,
        const int* __restrict__ offs3, const int* __restrict__ ends3,
        const u16* __restrict__ relT, const u16* __restrict__ gateT,
        const u16* __restrict__ vaT, const u16* __restrict__ W1T,
        const u16* __restrict__ fus2T, const u16* __restrict__ ftT,
        const u16* __restrict__ laT,
        const float* __restrict__ b1, const float* __restrict__ P,
        void* __restrict__ d_out) {
    const int f32 = flag[0];
    const u16* __restrict__ fb = f32 ? featB_ : (const u16*)feat;

    __shared__ __align__(16) u16 xA[MB * LDA];      // features, bf16 A-layout
    __shared__ __align__(16) u16 zb[2][MB * LDA];   // double-buffered z/agg/pe; reused as out staging
    __shared__ float wsn_s[2][MB];
    __shared__ float vsc_s[MB][3];
    __shared__ float red_s[4][MB][2];
    __shared__ float mrs_s[MB][2];
    __shared__ float aw_s[MB][3];
    __shared__ float natt_s[MB];
    __shared__ float lg_s[MB][2];
    __shared__ float vab1_s[64], vaw2_s[64];
    __shared__ float predw_s[256];
    __shared__ float b1_s[128], ftb_s[128], lng_s[128], lnb_s[128];

    const int tid = threadIdx.x;
    const int wid = tid >> 6;
    const int L = tid & 63, q = L >> 4, i = L & 15;
    const int nb = wid * 32;
    const int nodebase = blockIdx.x * MB;
    const int nl = tid >> 5, l32 = tid & 31, o4 = l32 * 4;
    const int gg = tid >> 4, l16 = tid & 15, o8 = l16 * 8;
    const f32x4 zz = {0.f, 0.f, 0.f, 0.f};

    auto ldf = [&](const u16* B, int row, int k0) -> bf16x8 {
        return *(const bf16x8*)&B[row * LDA + k0];
    };
    auto ldg = [&](const u16* B, int row, int k0) -> bf16x8 {
        return *(const bf16x8*)&B[row * 128 + k0];
    };
    // M=16 gemm: acc[nt], rows q*4+r, cols nb+nt*16+i
    auto gemm128 = [&](const u16* A, const u16* Bg, f32x4 acc[2]) {
        #pragma unroll
        for (int kk = 0; kk < 4; ++kk) {
            int k0 = q * 8 + kk * 32;
            bf16x8 a0 = ldf(A, i, k0);
            bf16x8 bb0 = ldg(Bg, nb + i, k0);
            bf16x8 bb1 = ldg(Bg, nb + 16 + i, k0);
            acc[0] = MFMA16x16x32(a0, bb0, acc[0], 0, 0, 0);
            acc[1] = MFMA16x16x32(a0, bb1, acc[1], 0, 0, 0);
        }
    };
    // gather: one node per 16-lane group; single 4-wide interleaved chain
    auto gather = [&](int v, u16* dst) {
        const int* offs = offs3 + v * N_;
        const int* ends = ends3 + v * N_;
        const int2* srcw = srcw3 + (size_t)v * E_;
        const int node = nodebase + gg;
        float z0 = 0.f, z1 = 0.f, z2 = 0.f, z3 = 0.f;
        float z4 = 0.f, z5 = 0.f, z6 = 0.f, z7 = 0.f, ws = 0.f;
        int j = offs[node], jend = ends[node];
        while (j < jend) {
            int r = jend - j;
            int2 e0 = srcw[j];
            int2 e1, e2, e3;
            e1.x = 0; e1.y = 0; e2.x = 0; e2.y = 0; e3.x = 0; e3.y = 0;
            if (r > 1) e1 = srcw[j + 1];
            if (r > 2) e2 = srcw[j + 2];
            if (r > 3) e3 = srcw[j + 3];
            uint4 x0, x1, x2, x3;
            x1.x = x1.y = x1.z = x1.w = 0;
            x2.x = x2.y = x2.z = x2.w = 0;
            x3.x = x3.y = x3.z = x3.w = 0;
            x0 = *(const uint4*)&fb[(size_t)e0.x * 128 + o8];
            if (r > 1) x1 = *(const uint4*)&fb[(size_t)e1.x * 128 + o8];
            if (r > 2) x2 = *(const uint4*)&fb[(size_t)e2.x * 128 + o8];
            if (r > 3) x3 = *(const uint4*)&fb[(size_t)e3.x * 128 + o8];
            float w0 = __int_as_float(e0.y), w1 = __int_as_float(e1.y);
            float w2 = __int_as_float(e2.y), w3 = __int_as_float(e3.y);
            ws += w0 + w1 + w2 + w3;
            z0 += w0 * blo(x0.x) + w1 * blo(x1.x) + w2 * blo(x2.x) + w3 * blo(x3.x);
            z1 += w0 * bhi(x0.x) + w1 * bhi(x1.x) + w2 * bhi(x2.x) + w3 * bhi(x3.x);
            z2 += w0 * blo(x0.y) + w1 * blo(x1.y) + w2 * blo(x2.y) + w3 * blo(x3.y);
            z3 += w0 * bhi(x0.y) + w1 * bhi(x1.y) + w2 * bhi(x2.y) + w3 * bhi(x3.y);
            z4 += w0 * blo(x0.z) + w1 * blo(x1.z) + w2 * blo(x2.z) + w3 * blo(x3.z);
            z5 += w0 * bhi(x0.z) + w1 * bhi(x1.z) + w2 * bhi(x2.z) + w3 * bhi(x3.z);
            z6 += w0 * blo(x0.w) + w1 * blo(x1.w) + w2 * blo(x2.w) + w3 * blo(x3.w);
            z7 += w0 * bhi(x0.w) + w1 * bhi(x1.w) + w2 * bhi(x2.w) + w3 * bhi(x3.w);
            j += 4;
        }
        uint4 u;
        u.x = (unsigned)f2b(z0) | ((unsigned)f2b(z1) << 16);
        u.y = (unsigned)f2b(z2) | ((unsigned)f2b(z3) << 16);
        u.z = (unsigned)f2b(z4) | ((unsigned)f2b(z5) << 16);
        u.w = (unsigned)f2b(z6) | ((unsigned)f2b(z7) << 16);
        *(uint4*)&dst[gg * LDA + o8] = u;
        if (l16 == 0) wsn_s[v & 1][gg] = ws;
    };

    // ---- phase 0: stage xA, consts, gather v0 ----
    {
        int m = tid >> 4, s = tid & 15;
        *(uint4*)&xA[m * LDA + s * 8] =
            *(const uint4*)&fb[(size_t)(nodebase + m) * 128 + s * 8];
    }
    if (tid < 64) { vab1_s[tid] = P[P_VAB1 + tid]; vaw2_s[tid] = P[P_VAW2 + tid]; }
    if (tid < 128) {
        b1_s[tid]  = b1[tid];
        ftb_s[tid] = P[P_FTB + tid];
        lng_s[tid] = P[P_LNG + tid];
        lnb_s[tid] = P[P_LNB + tid];
    }
    predw_s[tid] = P[P_PREDW + tid];
    gather(0, zb[0]);
    __syncthreads();                                               // B1

    // ---- label-aware attention ----
    f32x4 accL[2] = {zz, zz};
    gemm128(xA, laT, accL);
    #pragma unroll
    for (int rep = 0; rep < 2; ++rep) {
        int m = rep * 8 + nl;
        float lg0 = 0.f, lg1 = 0.f;
        #pragma unroll
        for (int t = 0; t < 4; ++t) {
            float xv = b2f(xA[m * LDA + o4 + t]);
            lg0 += xv * predw_s[(o4 + t) * 2 + 0];
            lg1 += xv * predw_s[(o4 + t) * 2 + 1];
        }
        #pragma unroll
        for (int s = 1; s <= 16; s <<= 1) {
            lg0 += __shfl_xor(lg0, s);
            lg1 += __shfl_xor(lg1, s);
        }
        if (l32 == 0) { lg_s[m][0] = lg0; lg_s[m][1] = lg1; }
    }
    {
        float la0 = P[P_LAB1 + nb + i],  la1 = P[P_LAB1 + nb + 16 + i];
        float lw0 = P[P_LAW2 + nb + i],  lw1 = P[P_LAW2 + nb + 16 + i];
        float partL[4];
        #pragma unroll
        for (int r = 0; r < 4; ++r) {
            float h0 = fmaxf(accL[0][r] + la0, 0.f);
            float h1 = fmaxf(accL[1][r] + la1, 0.f);
            partL[r] = h0 * lw0 + h1 * lw1;
        }
        #pragma unroll
        for (int s = 1; s <= 8; s <<= 1)
            #pragma unroll
            for (int r = 0; r < 4; ++r)
                partL[r] += __shfl_xor(partL[r], s);
        if (i == 0)
            #pragma unroll
            for (int r = 0; r < 4; ++r)
                red_s[wid][q * 4 + r][0] = partL[r];
    }
    __syncthreads();                                               // B2
    if (tid < MB) {
        float c0 = red_s[0][tid][0] + red_s[1][tid][0] + P[P_LAB2 + 0];
        float c1 = red_s[2][tid][0] + red_s[3][tid][0] + P[P_LAB2 + 1];
        float s0 = 1.f / (1.f + __expf(-c0));
        float s1 = 1.f / (1.f + __expf(-c1));
        float l0 = lg_s[tid][0] + P[P_PREDB + 0];
        float l1 = lg_s[tid][1] + P[P_PREDB + 1];
        float mx = fmaxf(l0, l1);
        float e0 = __expf(l0 - mx), e1 = __expf(l1 - mx);
        float inv = 1.f / (e0 + e1);
        float p0 = e0 * inv, p1 = e1 * inv;
        natt_s[tid] = s0 * p0 + s1 * p1 + P[P_ATTB];
        int node = nodebase + tid;
        if (f32) {
            float* pr = (float*)d_out + (size_t)N_ * O_;
            pr[node * 2 + 0] = p0; pr[node * 2 + 1] = p1;
        } else {
            u16* pr = (u16*)d_out + (size_t)N_ * O_;
            pr[node * 2 + 0] = f2b(p0); pr[node * 2 + 1] = f2b(p1);
        }
    }

    f32x4 viewr[3][2];
    #pragma unroll
    for (int v = 0; v < 3; ++v) {
        u16* zc = zb[v & 1];
        // ---- agg = z @ rel_w + wsn*rel_b ----
        f32x4 accA[2] = {zz, zz};
        gemm128(zc, relT + (size_t)v * 16384, accA);
        if (v < 2) gather(v + 1, zb[(v + 1) & 1]);     // other buffer; no hazard
        __syncthreads();                                           // B3
        {
            float rb0 = P[P_RELB + v * 128 + nb + i];
            float rb1 = P[P_RELB + v * 128 + nb + 16 + i];
            #pragma unroll
            for (int nt = 0; nt < 2; ++nt) {
                float rb = nt ? rb1 : rb0;
                int col = nb + nt * 16 + i;
                #pragma unroll
                for (int r = 0; r < 4; ++r) {
                    int row = q * 4 + r;
                    float a = accA[nt][r] + wsn_s[v & 1][row] * rb;
                    accA[nt][r] = a;
                    zc[row * LDA + col] = f2b(a);
                }
            }
        }
        __syncthreads();                                           // B4
        // ---- gate = sigmoid(agg @ gate_w + gb); view = gate*agg; pe -> zc ----
        f32x4 acc2[2] = {zz, zz};
        gemm128(zc, gateT + (size_t)v * 16384, acc2);
        __syncthreads();                                           // B5
        {
            float gb0 = P[P_GATEB + v * 128 + nb + i];
            float gb1 = P[P_GATEB + v * 128 + nb + 16 + i];
            float vp0 = P[P_VP + v * 128 + nb + i];
            float vp1 = P[P_VP + v * 128 + nb + 16 + i];
            #pragma unroll
            for (int nt = 0; nt < 2; ++nt) {
                float gb = nt ? gb1 : gb0, vp = nt ? vp1 : vp0;
                int col = nb + nt * 16 + i;
                #pragma unroll
                for (int r = 0; r < 4; ++r) {
                    int row = q * 4 + r;
                    float g = 1.f / (1.f + __expf(-(acc2[nt][r] + gb)));
                    float vv = g * accA[nt][r];
                    viewr[v][nt][r] = vv;
                    zc[row * LDA + col] = f2b(vv * vp);
                }
            }
        }
        __syncthreads();                                           // B6
        // ---- vh = relu(pe @ va_w1 + b); vscore = vh . va_w2 + b2 ----
        f32x4 accV = zz;
        const int nbv = wid * 16, colv = nbv + i;
        #pragma unroll
        for (int kk = 0; kk < 4; ++kk) {
            int k0 = q * 8 + kk * 32;
            bf16x8 a0 = ldf(zc, i, k0);
            bf16x8 bb = ldg(vaT, nbv + i, k0);
            accV = MFMA16x16x32(a0, bb, accV, 0, 0, 0);
        }
        float part[4];
        #pragma unroll
        for (int r = 0; r < 4; ++r) {
            float vh = fmaxf(accV[r] + vab1_s[colv], 0.f);
            part[r] = vh * vaw2_s[colv];
        }
        #pragma unroll
        for (int s = 1; s <= 8; s <<= 1)
            #pragma unroll
            for (int r = 0; r < 4; ++r)
                part[r] += __shfl_xor(part[r], s);
        if (i == 0)
            #pragma unroll
            for (int r = 0; r < 4; ++r)
                red_s[wid][q * 4 + r][0] = part[r];
        __syncthreads();                                           // B7
        if (tid < MB)
            vsc_s[tid][v] = red_s[0][tid][0] + red_s[1][tid][0] +
                            red_s[2][tid][0] + red_s[3][tid][0] + P[P_VAB2];
    }

    // ---- combine: softmax over views * natt -> wt ----
    if (tid < MB) {
        float s0 = vsc_s[tid][0], s1 = vsc_s[tid][1], s2 = vsc_s[tid][2];
        float mx = fmaxf(s0, fmaxf(s1, s2));
        float e0 = __expf(s0 - mx), e1 = __expf(s1 - mx), e2 = __expf(s2 - mx);
        float inv = natt_s[tid] / (e0 + e1 + e2);
        aw_s[tid][0] = e0 * inv; aw_s[tid][1] = e1 * inv; aw_s[tid][2] = e2 * inv;
    }
    __syncthreads();                                               // B8
    u16* wt = zb[0];     // zb[0] (pe of v2) fully consumed before B7(v2)
    #pragma unroll
    for (int nt = 0; nt < 2; ++nt)
        #pragma unroll
        for (int r = 0; r < 4; ++r) {
            int row = q * 4 + r, col = nb + nt * 16 + i;
            float wv = aw_s[row][0] * viewr[0][nt][r] +
                       aw_s[row][1] * viewr[1][nt][r] +
                       aw_s[row][2] * viewr[2][nt][r];
            wt[row * LDA + col] = f2b(wv);
        }
    f32x4 accF[2] = {zz, zz};
    gemm128(xA, W1T, accF);
    __syncthreads();                                               // B9
    gemm128(wt, fus2T, accF);     // accF += wt @ fus_w[128:]
    float fR[2][4];
    #pragma unroll
    for (int nt = 0; nt < 2; ++nt)
        #pragma unroll
        for (int r = 0; r < 4; ++r) {
            int col = nb + nt * 16 + i;
            fR[nt][r] = fmaxf(accF[nt][r] + b1_s[col], 0.f);
        }
    f32x4 accT[2] = {zz, zz};
    gemm128(xA, ftT, accT);

    // ---- out = f + X@ft_w + ft_b, LayerNorm ----
    float ov[2][4], ps[4], pq[4];
    #pragma unroll
    for (int r = 0; r < 4; ++r) { ps[r] = 0.f; pq[r] = 0.f; }
    #pragma unroll
    for (int nt = 0; nt < 2; ++nt)
        #pragma unroll
        for (int r = 0; r < 4; ++r) {
            int col = nb + nt * 16 + i;
            float o = fR[nt][r] + accT[nt][r] + ftb_s[col];
            ov[nt][r] = o;
            ps[r] += o; pq[r] += o * o;
        }
    #pragma unroll
    for (int s = 1; s <= 8; s <<= 1)
        #pragma unroll
        for (int r = 0; r < 4; ++r) {
            ps[r] += __shfl_xor(ps[r], s);
            pq[r] += __shfl_xor(pq[r], s);
        }
    if (i == 0)
        #pragma unroll
        for (int r = 0; r < 4; ++r) {
            red_s[wid][q * 4 + r][0] = ps[r];
            red_s[wid][q * 4 + r][1] = pq[r];
        }
    __syncthreads();                                               // B10
    if (tid < MB) {
        float sm = red_s[0][tid][0] + red_s[1][tid][0] + red_s[2][tid][0] + red_s[3][tid][0];
        float sq = red_s[0][tid][1] + red_s[1][tid][1] + red_s[2][tid][1] + red_s[3][tid][1];
        float mu = sm * (1.f / 128.f);
        float var = sq * (1.f / 128.f) - mu * mu;
        mrs_s[tid][0] = mu; mrs_s[tid][1] = rsqrtf(var + 1e-5f);
    }
    __syncthreads();                                               // B11
    float* outf = (float*)zb;    // zb free: wt consumed before B10
    u16*   outb = (u16*)zb;
    #pragma unroll
    for (int nt = 0; nt < 2; ++nt)
        #pragma unroll
        for (int r = 0; r < 4; ++r) {
            int row = q * 4 + r, col = nb + nt * 16 + i;
            float val = (ov[nt][r] - mrs_s[row][0]) * mrs_s[row][1]
                        * lng_s[col] + lnb_s[col];
            if (f32) outf[row * 128 + col] = val;
            else     outb[row * 128 + col] = f2b(val);
        }
    __syncthreads();                                               // B12
    if (f32) {
        float* op = (float*)d_out + (size_t)nodebase * 128;
        for (int idx = tid; idx < 512; idx += 256)
            ((float4*)op)[idx] = ((const float4*)outf)[idx];
    } else {
        u16* op = (u16*)d_out + (size_t)nodebase * 128;
        ((uint4*)op)[tid] = ((const uint4*)outb)[tid];
    }
}

extern "C" void kernel_launch(void* const* d_in, const int* in_sizes, int n_in,
                              void* d_out, int out_size, void* d_ws, size_t ws_size,
                              hipStream_t stream) {
    const void* feat     = d_in[0];
    const int*  ei       = (const int*)d_in[1];
    const void* ew       = d_in[2];
    const void* rel_w    = d_in[3];
    const void* rel_b    = d_in[4];
    const void* gate_w   = d_in[5];
    const void* gate_b   = d_in[6];
    const void* la_w1    = d_in[7];
    const void* la_b1    = d_in[8];
    const void* la_w2    = d_in[9];
    const void* la_b2    = d_in[10];
    const void* pred_w   = d_in[11];
    const void* pred_b   = d_in[12];
    const void* att_bias = d_in[13];
    const void* view_pref= d_in[14];
    const void* va_w1    = d_in[15];
    const void* va_b1    = d_in[16];
    const void* va_w2    = d_in[17];
    const void* va_b2    = d_in[18];
    const void* ft_w     = d_in[19];
    const void* ft_b     = d_in[20];
    const void* sl_w     = d_in[21];
    const void* sl_b     = d_in[22];
    const void* fus_w    = d_in[23];
    const void* fus_b    = d_in[24];
    const void* ln_g     = d_in[25];
    const void* ln_beta  = d_in[26];

    // workspace layout (~38 MB total)
    int*   flag  = (int*)d_ws;                    // 4 ints
    int*   offs3 = flag + 4;                      // 3N
    int*   cur3  = offs3 + 3 * N_;                // 3N
    int2*  srcw3 = (int2*)(cur3 + 3 * N_);        // 3E int2 (16B-aligned)
    int*   bsum  = (int*)(srcw3 + 3 * E_);        // 3*128
    float* b1    = (float*)(bsum + 3 * 128);      // 128
    float* P     = b1 + 128;                      // 2182 (pad to 2304)
    u16*   W1T   = (u16*)(P + 2304);              // 16384
    u16*   relT  = W1T + 16384;                   // 3*16384
    u16*   gateT = relT + 3 * 16384;              // 3*16384
    u16*   vaT   = gateT + 3 * 16384;             // 8192
    u16*   fus2T = vaT + 8192;                    // 16384
    u16*   ftT   = fus2T + 16384;                 // 16384
    u16*   laT   = ftT + 16384;                   // 16384
    u16*   featB = laT + 16384;                   // N*128 bf16 (f32 input case)

    k_detect<<<1, 64, 0, stream>>>((const u16*)feat, flag);
    (void)hipMemsetAsync(cur3, 0, 3 * N_ * sizeof(int), stream);
    k_preC<<<PRE_TOT, 256, 0, stream>>>(flag, feat, featB,
                                        sl_w, sl_b, fus_w, fus_b, W1T, b1,
                                        rel_w, gate_w, va_w1, ft_w, la_w1,
                                        rel_b, gate_b, view_pref,
                                        va_b1, va_w2, va_b2,
                                        la_b1, la_w2, la_b2,
                                        pred_b, att_bias, ft_b, ln_g, ln_beta, pred_w,
                                        relT, gateT, vaT, fus2T, ftT, laT, P,
                                        ei, cur3);
    k_scan_bsum<<<3 * NB_SCAN, 256, 0, stream>>>(cur3, bsum);
    k_scan_write<<<3 * NB_SCAN, 256, 0, stream>>>(cur3, bsum, offs3);
    k_place<<<3 * EGRID, 256, 0, stream>>>(flag, ei, ew, cur3, srcw3);
    k_fused<<<NBLK, 256, 0, stream>>>(flag, feat, featB, srcw3, offs3, cur3,
                                      relT, gateT, vaT, W1T, fus2T, ftT, laT,
                                      b1, P, d_out);
}

// Round 4
// 623.945 us; speedup vs baseline: 1.0993x; 1.0993x over previous
//
#include <hip/hip_runtime.h>

#define N_ 100000
#define D_ 128
#define O_ 128
#define V_ 3
#define E_ 400000
#define NB_SCAN 98   // ceil(N/1024)
#define EGRID 1563   // ceil(E/256)
#define MB 16        // nodes per k_fused block (one node per 16-lane group)
#define NBLK (N_ / MB)   // 6250
#define LDA 136      // padded bf16 row stride (16B-aligned)

// fused pre-kernel block ranges
#define PRE_CVT  6250                   // feature cvt (f32 path only)
#define PRE_PREW (PRE_CVT + 64)         // 6314
#define PRE_PREP (PRE_PREW + 617)       // 6931
#define PRE_TOT  (PRE_PREP + 3 * EGRID) // 11620

typedef unsigned short u16;
typedef __attribute__((ext_vector_type(8))) short bf16x8;   // 8 bf16 = 4 VGPRs
typedef __attribute__((ext_vector_type(4))) float f32x4;

#define MFMA16x16x32 __builtin_amdgcn_mfma_f32_16x16x32_bf16

// ---- fp32 param block offsets (in workspace, filled by prep) ----
#define P_RELB  0
#define P_GATEB 384
#define P_VP    768
#define P_VAB1  1152
#define P_VAW2  1216
#define P_VAB2  1280
#define P_LAB1  1281
#define P_LAW2  1409
#define P_LAB2  1537
#define P_PREDB 1539
#define P_ATTB  1541
#define P_FTB   1542
#define P_LNG   1670
#define P_LNB   1798
#define P_PREDW 1926
#define P_TOTAL 2182

__device__ __forceinline__ float b2f(u16 u) {
    union { float f; unsigned int i; } x; x.i = ((unsigned int)u) << 16; return x.f;
}
__device__ __forceinline__ float blo(unsigned int u) {
    union { float f; unsigned int i; } x; x.i = u << 16; return x.f;
}
__device__ __forceinline__ float bhi(unsigned int u) {
    union { float f; unsigned int i; } x; x.i = u & 0xffff0000u; return x.f;
}
__device__ __forceinline__ u16 f2b(float f) {
    union { float f; unsigned int i; } x; x.f = f;
    unsigned int r = x.i + 0x7FFFu + ((x.i >> 16) & 1u);
    return (u16)(r >> 16);
}

template<int F32> __device__ __forceinline__ float LD(const void* p, size_t i) {
    if (F32) return ((const float*)p)[i];
    return b2f(((const u16*)p)[i]);
}

// ---------------- dtype detector: fp32 vs bf16 element stream ----------------
__global__ void k_detect(const u16* __restrict__ feat, int* __restrict__ flag) {
    int t = threadIdx.x;   // 64 lanes; check feat[2i], i = t and t+64
    u16 a = feat[2 * t], b = feat[2 * t + 128];
    int zeros = (a == 0 ? 1 : 0) + (b == 0 ? 1 : 0);
    float va = b2f(a), vb = b2f(b);
    int bad = (!(va > -128.f && va < 128.f) ? 1 : 0) +
              (!(vb > -128.f && vb < 128.f) ? 1 : 0);
    #pragma unroll
    for (int s = 1; s <= 32; s <<= 1) {
        bad += __shfl_xor(bad, s);
        zeros += __shfl_xor(zeros, s);
    }
    if (t == 0) flag[0] = (bad >= 16 || zeros >= 64) ? 1 : 0;
}

// ---------------- fused pre kernel: cvt | prew | prep | count ----------------
__device__ __forceinline__ void cvt_body_f32(int b, const void* feat,
                                             u16* __restrict__ featB) {
    size_t idx = (size_t)b * 256 + threadIdx.x;   // 8 elems per thread
    const float4* fp = (const float4*)feat;
    float4 a = fp[idx * 2], c = fp[idx * 2 + 1];
    uint4 u;
    u.x = (unsigned)f2b(a.x) | ((unsigned)f2b(a.y) << 16);
    u.y = (unsigned)f2b(a.z) | ((unsigned)f2b(a.w) << 16);
    u.z = (unsigned)f2b(c.x) | ((unsigned)f2b(c.y) << 16);
    u.w = (unsigned)f2b(c.z) | ((unsigned)f2b(c.w) << 16);
    ((uint4*)featB)[idx] = u;
}

template<int F32>
__device__ __forceinline__ void prew_body(int b, const void* sl_w, const void* sl_b,
                                          const void* fus_w, const void* fus_b,
                                          u16* __restrict__ W1T, float* __restrict__ b1) {
    int gid = b * 256 + threadIdx.x;   // 64 blocks
    int d = gid >> 7, o = gid & 127;
    float acc = 0.f;
    for (int k = 0; k < 128; ++k)
        acc += LD<F32>(sl_w, d * 128 + k) * LD<F32>(fus_w, k * 128 + o);
    W1T[o * 128 + d] = f2b(acc);
    if (gid < 128) {
        float accb = 0.f;
        for (int k = 0; k < 128; ++k)
            accb += LD<F32>(sl_b, k) * LD<F32>(fus_w, k * 128 + gid);
        b1[gid] = accb + LD<F32>(fus_b, gid);
    }
}

template<int F32>
__device__ __forceinline__ void prep_body(int b,
        const void* rel_w, const void* gate_w, const void* va_w1, const void* fus_w,
        const void* ft_w, const void* la_w1,
        const void* rel_b, const void* gate_b, const void* vpref,
        const void* va_b1, const void* va_w2, const void* va_b2,
        const void* la_b1, const void* la_w2, const void* la_b2,
        const void* pred_b, const void* att_bias, const void* ft_b,
        const void* ln_g, const void* ln_beta, const void* pred_w,
        u16* __restrict__ relT, u16* __restrict__ gateT, u16* __restrict__ vaT,
        u16* __restrict__ fus2T, u16* __restrict__ ftT, u16* __restrict__ laT,
        float* __restrict__ P) {
    int id = b * 256 + threadIdx.x;
    if (id < 49152) {
        int v = id >> 14, r = id & 16383, o = r >> 7, d = r & 127;
        relT[id] = f2b(LD<F32>(rel_w, (size_t)v * 16384 + d * 128 + o));
    } else if (id < 98304) {
        int t = id - 49152, v = t >> 14, r = t & 16383, o = r >> 7, d = r & 127;
        gateT[t] = f2b(LD<F32>(gate_w, (size_t)v * 16384 + d * 128 + o));
    } else if (id < 106496) {
        int t = id - 98304, n = t >> 7, k = t & 127;
        vaT[t] = f2b(LD<F32>(va_w1, k * 64 + n));
    } else if (id < 122880) {
        int t = id - 106496, n = t >> 7, k = t & 127;
        fus2T[t] = f2b(LD<F32>(fus_w, (128 + k) * 128 + n));
    } else if (id < 139264) {
        int t = id - 122880, o = t >> 7, d = t & 127;
        ftT[t] = f2b(LD<F32>(ft_w, d * 128 + o));
    } else if (id < 155648) {
        int t = id - 139264, n = t >> 7, d = t & 127;
        int c = n >> 6, j = n & 63;
        laT[t] = f2b(LD<F32>(la_w1, c * 8192 + d * 64 + j));
    } else if (id < 155648 + P_TOTAL) {
        int t = id - 155648;
        float val;
        if      (t < P_GATEB) val = LD<F32>(rel_b, t);
        else if (t < P_VP)    val = LD<F32>(gate_b, t - P_GATEB);
        else if (t < P_VAB1)  val = LD<F32>(vpref, t - P_VP);
        else if (t < P_VAW2)  val = LD<F32>(va_b1, t - P_VAB1);
        else if (t < P_VAB2)  val = LD<F32>(va_w2, t - P_VAW2);
        else if (t < P_LAB1)  val = LD<F32>(va_b2, 0);
        else if (t < P_LAW2)  val = LD<F32>(la_b1, t - P_LAB1);
        else if (t < P_LAB2)  val = LD<F32>(la_w2, t - P_LAW2);
        else if (t < P_PREDB) val = LD<F32>(la_b2, t - P_LAB2);
        else if (t < P_ATTB)  val = LD<F32>(pred_b, t - P_PREDB);
        else if (t < P_FTB)   val = LD<F32>(att_bias, 0);
        else if (t < P_LNG)   val = LD<F32>(ft_b, t - P_FTB);
        else if (t < P_LNB)   val = LD<F32>(ln_g, t - P_LNG);
        else if (t < P_PREDW) val = LD<F32>(ln_beta, t - P_LNB);
        else                  val = LD<F32>(pred_w, t - P_PREDW);
        P[t] = val;
    }
}

__global__ __launch_bounds__(256) void k_preC(const int* __restrict__ flag,
        const void* feat, u16* __restrict__ featB,
        const void* sl_w, const void* sl_b, const void* fus_w, const void* fus_b,
        u16* __restrict__ W1T, float* __restrict__ b1,
        const void* rel_w, const void* gate_w, const void* va_w1,
        const void* ft_w, const void* la_w1,
        const void* rel_b, const void* gate_b, const void* vpref,
        const void* va_b1, const void* va_w2, const void* va_b2,
        const void* la_b1, const void* la_w2, const void* la_b2,
        const void* pred_b, const void* att_bias, const void* ft_b,
        const void* ln_g, const void* ln_beta, const void* pred_w,
        u16* __restrict__ relT, u16* __restrict__ gateT, u16* __restrict__ vaT,
        u16* __restrict__ fus2T, u16* __restrict__ ftT, u16* __restrict__ laT,
        float* __restrict__ P,
        const int* __restrict__ ei, int* __restrict__ cur3) {
    int b = blockIdx.x;
    if (b < PRE_CVT) {
        if (flag[0]) cvt_body_f32(b, feat, featB);   // bf16 case: featB unused
    } else if (b < PRE_PREW) {
        if (flag[0]) prew_body<1>(b - PRE_CVT, sl_w, sl_b, fus_w, fus_b, W1T, b1);
        else         prew_body<0>(b - PRE_CVT, sl_w, sl_b, fus_w, fus_b, W1T, b1);
    } else if (b < PRE_PREP) {
        if (flag[0]) prep_body<1>(b - PRE_PREW, rel_w, gate_w, va_w1, fus_w, ft_w, la_w1,
                                  rel_b, gate_b, vpref, va_b1, va_w2, va_b2,
                                  la_b1, la_w2, la_b2, pred_b, att_bias, ft_b,
                                  ln_g, ln_beta, pred_w, relT, gateT, vaT, fus2T, ftT, laT, P);
        else         prep_body<0>(b - PRE_PREW, rel_w, gate_w, va_w1, fus_w, ft_w, la_w1,
                                  rel_b, gate_b, vpref, va_b1, va_w2, va_b2,
                                  la_b1, la_w2, la_b2, pred_b, att_bias, ft_b,
                                  ln_g, ln_beta, pred_w, relT, gateT, vaT, fus2T, ftT, laT, P);
    } else {
        int b2 = b - PRE_PREP;
        int v = b2 / EGRID;
        int e = (b2 % EGRID) * 256 + threadIdx.x;
        if (e < E_) atomicAdd(&cur3[v * N_ + ei[(size_t)v * 2 * E_ + E_ + e]], 1);
    }
}

// ---------------- CSR scan: bsum / write (inline spine) ----------------------
__global__ __launch_bounds__(256) void k_scan_bsum(const int* __restrict__ cur3,
                                                   int* __restrict__ bsum) {
    __shared__ int red[256];
    const int v = blockIdx.x / NB_SCAN, b = blockIdx.x % NB_SCAN, tid = threadIdx.x;
    const int base = b * 1024;
    const int* counts = cur3 + v * N_;
    int s = 0;
    for (int i = tid; i < 1024; i += 256) {
        int idx = base + i;
        s += (idx < N_) ? counts[idx] : 0;
    }
    red[tid] = s;
    __syncthreads();
    for (int st = 128; st >= 1; st >>= 1) {
        if (tid < st) red[tid] += red[tid + st];
        __syncthreads();
    }
    if (tid == 0) bsum[v * 128 + b] = red[0];
}

__global__ __launch_bounds__(256) void k_scan_write(int* __restrict__ cur3,
                                                    const int* __restrict__ bsum,
                                                    int* __restrict__ offs3) {
    __shared__ int lsum[256];
    __shared__ int bs_s[128];
    const int v = blockIdx.x / NB_SCAN, b = blockIdx.x % NB_SCAN, tid = threadIdx.x;
    const int base = b * 1024;
    int* counts = cur3 + v * N_;
    int* offs   = offs3 + v * N_;
    if (tid < 128) bs_s[tid] = (tid < b) ? bsum[v * 128 + tid] : 0;
    int c[4]; int s = 0;
    #pragma unroll
    for (int k = 0; k < 4; ++k) {
        int idx = base + tid * 4 + k;
        c[k] = (idx < N_) ? counts[idx] : 0;
        s += c[k];
    }
    lsum[tid] = s;
    __syncthreads();
    for (int st = 1; st < 256; st <<= 1) {
        int t = (tid >= st) ? lsum[tid - st] : 0;
        __syncthreads();
        lsum[tid] += t;
        __syncthreads();
    }
    for (int st = 64; st >= 1; st >>= 1) {
        if (tid < st) bs_s[tid] += bs_s[tid + st];
        __syncthreads();
    }
    int off = bs_s[0] + lsum[tid] - s;
    #pragma unroll
    for (int k = 0; k < 4; ++k) {
        int idx = base + tid * 4 + k;
        if (idx < N_) { offs[idx] = off; counts[idx] = off; }
        off += c[k];
    }
}

// place: srcw[pos] = {src, weight-bits}
template<int F32>
__device__ __forceinline__ void place_body(const int* __restrict__ ei, const void* ew_all,
                                           int* __restrict__ cur3, int2* __restrict__ srcw3) {
    int v = blockIdx.x / EGRID;
    int e = (blockIdx.x % EGRID) * 256 + threadIdx.x;
    if (e < E_) {
        int dst = ei[(size_t)v * 2 * E_ + E_ + e];
        int src = ei[(size_t)v * 2 * E_ + e];
        float w = LD<F32>(ew_all, (size_t)v * E_ + e);
        int pos = atomicAdd(&cur3[v * N_ + dst], 1);
        int2 sw; sw.x = src; sw.y = __float_as_int(w);
        srcw3[(size_t)v * E_ + pos] = sw;
    }
    // afterwards cur3[v*N+n] == row end
}
__global__ __launch_bounds__(256) void k_place(const int* __restrict__ flag,
                                               const int* __restrict__ ei, const void* ew,
                                               int* __restrict__ cur3, int2* __restrict__ srcw3) {
    if (flag[0]) place_body<1>(ei, ew, cur3, srcw3);
    else         place_body<0>(ei, ew, cur3, srcw3);
}

// ------ fused MFMA pipeline: MB=16, one node per 16-lane group ---------------
// LDS ~18 KB; launch_bounds (256,4): 128-VGPR cap -> ZERO spill (round-3's
// (256,8)/64-cap spilled ~290 MB each way to scratch). 4 blocks/CU.
__global__ __launch_bounds__(256, 4) void k_fused(const int* __restrict__ flag,
        const void* feat, const u16* __restrict__ featB_,
        const int2* __restrict__ srcw3,
        const int* __restrict__ offs3, const int* __restrict__ ends3,
        const u16* __restrict__ relT, const u16* __restrict__ gateT,
        const u16* __restrict__ vaT, const u16* __restrict__ W1T,
        const u16* __restrict__ fus2T, const u16* __restrict__ ftT,
        const u16* __restrict__ laT,
        const float* __restrict__ b1, const float* __restrict__ P,
        void* __restrict__ d_out) {
    const int f32 = flag[0];
    const u16* __restrict__ fb = f32 ? featB_ : (const u16*)feat;

    __shared__ __align__(16) u16 xA[MB * LDA];      // features, bf16 A-layout
    __shared__ __align__(16) u16 zb[2][MB * LDA];   // double-buffered z/agg/pe; reused as out staging
    __shared__ float wsn_s[2][MB];
    __shared__ float vsc_s[MB][3];
    __shared__ float red_s[4][MB][2];
    __shared__ float mrs_s[MB][2];
    __shared__ float aw_s[MB][3];
    __shared__ float natt_s[MB];
    __shared__ float lg_s[MB][2];
    __shared__ float vab1_s[64], vaw2_s[64];
    __shared__ float predw_s[256];
    __shared__ float b1_s[128], ftb_s[128], lng_s[128], lnb_s[128];

    const int tid = threadIdx.x;
    const int wid = tid >> 6;
    const int L = tid & 63, q = L >> 4, i = L & 15;
    const int nb = wid * 32;
    const int nodebase = blockIdx.x * MB;
    const int nl = tid >> 5, l32 = tid & 31, o4 = l32 * 4;
    const int gg = tid >> 4, l16 = tid & 15, o8 = l16 * 8;
    const f32x4 zz = {0.f, 0.f, 0.f, 0.f};

    auto ldf = [&](const u16* B, int row, int k0) -> bf16x8 {
        return *(const bf16x8*)&B[row * LDA + k0];
    };
    auto ldg = [&](const u16* B, int row, int k0) -> bf16x8 {
        return *(const bf16x8*)&B[row * 128 + k0];
    };
    // M=16 gemm: acc[nt], rows q*4+r, cols nb+nt*16+i
    auto gemm128 = [&](const u16* A, const u16* Bg, f32x4 acc[2]) {
        #pragma unroll
        for (int kk = 0; kk < 4; ++kk) {
            int k0 = q * 8 + kk * 32;
            bf16x8 a0 = ldf(A, i, k0);
            bf16x8 bb0 = ldg(Bg, nb + i, k0);
            bf16x8 bb1 = ldg(Bg, nb + 16 + i, k0);
            acc[0] = MFMA16x16x32(a0, bb0, acc[0], 0, 0, 0);
            acc[1] = MFMA16x16x32(a0, bb1, acc[1], 0, 0, 0);
        }
    };
    // gather: one node per 16-lane group; single 4-wide interleaved chain
    auto gather = [&](int v, u16* dst) {
        const int* offs = offs3 + v * N_;
        const int* ends = ends3 + v * N_;
        const int2* srcw = srcw3 + (size_t)v * E_;
        const int node = nodebase + gg;
        float z0 = 0.f, z1 = 0.f, z2 = 0.f, z3 = 0.f;
        float z4 = 0.f, z5 = 0.f, z6 = 0.f, z7 = 0.f, ws = 0.f;
        int j = offs[node], jend = ends[node];
        while (j < jend) {
            int r = jend - j;
            int2 e0 = srcw[j];
            int2 e1, e2, e3;
            e1.x = 0; e1.y = 0; e2.x = 0; e2.y = 0; e3.x = 0; e3.y = 0;
            if (r > 1) e1 = srcw[j + 1];
            if (r > 2) e2 = srcw[j + 2];
            if (r > 3) e3 = srcw[j + 3];
            uint4 x0, x1, x2, x3;
            x1.x = x1.y = x1.z = x1.w = 0;
            x2.x = x2.y = x2.z = x2.w = 0;
            x3.x = x3.y = x3.z = x3.w = 0;
            x0 = *(const uint4*)&fb[(size_t)e0.x * 128 + o8];
            if (r > 1) x1 = *(const uint4*)&fb[(size_t)e1.x * 128 + o8];
            if (r > 2) x2 = *(const uint4*)&fb[(size_t)e2.x * 128 + o8];
            if (r > 3) x3 = *(const uint4*)&fb[(size_t)e3.x * 128 + o8];
            float w0 = __int_as_float(e0.y), w1 = __int_as_float(e1.y);
            float w2 = __int_as_float(e2.y), w3 = __int_as_float(e3.y);
            ws += w0 + w1 + w2 + w3;
            z0 += w0 * blo(x0.x) + w1 * blo(x1.x) + w2 * blo(x2.x) + w3 * blo(x3.x);
            z1 += w0 * bhi(x0.x) + w1 * bhi(x1.x) + w2 * bhi(x2.x) + w3 * bhi(x3.x);
            z2 += w0 * blo(x0.y) + w1 * blo(x1.y) + w2 * blo(x2.y) + w3 * blo(x3.y);
            z3 += w0 * bhi(x0.y) + w1 * bhi(x1.y) + w2 * bhi(x2.y) + w3 * bhi(x3.y);
            z4 += w0 * blo(x0.z) + w1 * blo(x1.z) + w2 * blo(x2.z) + w3 * blo(x3.z);
            z5 += w0 * bhi(x0.z) + w1 * bhi(x1.z) + w2 * bhi(x2.z) + w3 * bhi(x3.z);
            z6 += w0 * blo(x0.w) + w1 * blo(x1.w) + w2 * blo(x2.w) + w3 * blo(x3.w);
            z7 += w0 * bhi(x0.w) + w1 * bhi(x1.w) + w2 * bhi(x2.w) + w3 * bhi(x3.w);
            j += 4;
        }
        uint4 u;
        u.x = (unsigned)f2b(z0) | ((unsigned)f2b(z1) << 16);
        u.y = (unsigned)f2b(z2) | ((unsigned)f2b(z3) << 16);
        u.z = (unsigned)f2b(z4) | ((unsigned)f2b(z5) << 16);
        u.w = (unsigned)f2b(z6) | ((unsigned)f2b(z7) << 16);
        *(uint4*)&dst[gg * LDA + o8] = u;
        if (l16 == 0) wsn_s[v & 1][gg] = ws;
    };

    // ---- phase 0: stage xA, consts, gather v0 ----
    {
        int m = tid >> 4, s = tid & 15;
        *(uint4*)&xA[m * LDA + s * 8] =
            *(const uint4*)&fb[(size_t)(nodebase + m) * 128 + s * 8];
    }
    if (tid < 64) { vab1_s[tid] = P[P_VAB1 + tid]; vaw2_s[tid] = P[P_VAW2 + tid]; }
    if (tid < 128) {
        b1_s[tid]  = b1[tid];
        ftb_s[tid] = P[P_FTB + tid];
        lng_s[tid] = P[P_LNG + tid];
        lnb_s[tid] = P[P_LNB + tid];
    }
    predw_s[tid] = P[P_PREDW + tid];
    gather(0, zb[0]);
    __syncthreads();                                               // B1

    // ---- label-aware attention ----
    f32x4 accL[2] = {zz, zz};
    gemm128(xA, laT, accL);
    #pragma unroll
    for (int rep = 0; rep < 2; ++rep) {
        int m = rep * 8 + nl;
        float lg0 = 0.f, lg1 = 0.f;
        #pragma unroll
        for (int t = 0; t < 4; ++t) {
            float xv = b2f(xA[m * LDA + o4 + t]);
            lg0 += xv * predw_s[(o4 + t) * 2 + 0];
            lg1 += xv * predw_s[(o4 + t) * 2 + 1];
        }
        #pragma unroll
        for (int s = 1; s <= 16; s <<= 1) {
            lg0 += __shfl_xor(lg0, s);
            lg1 += __shfl_xor(lg1, s);
        }
        if (l32 == 0) { lg_s[m][0] = lg0; lg_s[m][1] = lg1; }
    }
    {
        float la0 = P[P_LAB1 + nb + i],  la1 = P[P_LAB1 + nb + 16 + i];
        float lw0 = P[P_LAW2 + nb + i],  lw1 = P[P_LAW2 + nb + 16 + i];
        float partL[4];
        #pragma unroll
        for (int r = 0; r < 4; ++r) {
            float h0 = fmaxf(accL[0][r] + la0, 0.f);
            float h1 = fmaxf(accL[1][r] + la1, 0.f);
            partL[r] = h0 * lw0 + h1 * lw1;
        }
        #pragma unroll
        for (int s = 1; s <= 8; s <<= 1)
            #pragma unroll
            for (int r = 0; r < 4; ++r)
                partL[r] += __shfl_xor(partL[r], s);
        if (i == 0)
            #pragma unroll
            for (int r = 0; r < 4; ++r)
                red_s[wid][q * 4 + r][0] = partL[r];
    }
    __syncthreads();                                               // B2
    if (tid < MB) {
        float c0 = red_s[0][tid][0] + red_s[1][tid][0] + P[P_LAB2 + 0];
        float c1 = red_s[2][tid][0] + red_s[3][tid][0] + P[P_LAB2 + 1];
        float s0 = 1.f / (1.f + __expf(-c0));
        float s1 = 1.f / (1.f + __expf(-c1));
        float l0 = lg_s[tid][0] + P[P_PREDB + 0];
        float l1 = lg_s[tid][1] + P[P_PREDB + 1];
        float mx = fmaxf(l0, l1);
        float e0 = __expf(l0 - mx), e1 = __expf(l1 - mx);
        float inv = 1.f / (e0 + e1);
        float p0 = e0 * inv, p1 = e1 * inv;
        natt_s[tid] = s0 * p0 + s1 * p1 + P[P_ATTB];
        int node = nodebase + tid;
        if (f32) {
            float* pr = (float*)d_out + (size_t)N_ * O_;
            pr[node * 2 + 0] = p0; pr[node * 2 + 1] = p1;
        } else {
            u16* pr = (u16*)d_out + (size_t)N_ * O_;
            pr[node * 2 + 0] = f2b(p0); pr[node * 2 + 1] = f2b(p1);
        }
    }

    f32x4 viewr[3][2];
    #pragma unroll
    for (int v = 0; v < 3; ++v) {
        u16* zc = zb[v & 1];
        // ---- agg = z @ rel_w + wsn*rel_b ----
        f32x4 accA[2] = {zz, zz};
        gemm128(zc, relT + (size_t)v * 16384, accA);
        if (v < 2) gather(v + 1, zb[(v + 1) & 1]);     // other buffer; no hazard
        __syncthreads();                                           // B3
        {
            float rb0 = P[P_RELB + v * 128 + nb + i];
            float rb1 = P[P_RELB + v * 128 + nb + 16 + i];
            #pragma unroll
            for (int nt = 0; nt < 2; ++nt) {
                float rb = nt ? rb1 : rb0;
                int col = nb + nt * 16 + i;
                #pragma unroll
                for (int r = 0; r < 4; ++r) {
                    int row = q * 4 + r;
                    float a = accA[nt][r] + wsn_s[v & 1][row] * rb;
                    accA[nt][r] = a;
                    zc[row * LDA + col] = f2b(a);
                }
            }
        }
        __syncthreads();                                           // B4
        // ---- gate = sigmoid(agg @ gate_w + gb); view = gate*agg; pe -> zc ----
        f32x4 acc2[2] = {zz, zz};
        gemm128(zc, gateT + (size_t)v * 16384, acc2);
        __syncthreads();                                           // B5
        {
            float gb0 = P[P_GATEB + v * 128 + nb + i];
            float gb1 = P[P_GATEB + v * 128 + nb + 16 + i];
            float vp0 = P[P_VP + v * 128 + nb + i];
            float vp1 = P[P_VP + v * 128 + nb + 16 + i];
            #pragma unroll
            for (int nt = 0; nt < 2; ++nt) {
                float gb = nt ? gb1 : gb0, vp = nt ? vp1 : vp0;
                int col = nb + nt * 16 + i;
                #pragma unroll
                for (int r = 0; r < 4; ++r) {
                    int row = q * 4 + r;
                    float g = 1.f / (1.f + __expf(-(acc2[nt][r] + gb)));
                    float vv = g * accA[nt][r];
                    viewr[v][nt][r] = vv;
                    zc[row * LDA + col] = f2b(vv * vp);
                }
            }
        }
        __syncthreads();                                           // B6
        // ---- vh = relu(pe @ va_w1 + b); vscore = vh . va_w2 + b2 ----
        f32x4 accV = zz;
        const int nbv = wid * 16, colv = nbv + i;
        #pragma unroll
        for (int kk = 0; kk < 4; ++kk) {
            int k0 = q * 8 + kk * 32;
            bf16x8 a0 = ldf(zc, i, k0);
            bf16x8 bb = ldg(vaT, nbv + i, k0);
            accV = MFMA16x16x32(a0, bb, accV, 0, 0, 0);
        }
        float part[4];
        #pragma unroll
        for (int r = 0; r < 4; ++r) {
            float vh = fmaxf(accV[r] + vab1_s[colv], 0.f);
            part[r] = vh * vaw2_s[colv];
        }
        #pragma unroll
        for (int s = 1; s <= 8; s <<= 1)
            #pragma unroll
            for (int r = 0; r < 4; ++r)
                part[r] += __shfl_xor(part[r], s);
        if (i == 0)
            #pragma unroll
            for (int r = 0; r < 4; ++r)
                red_s[wid][q * 4 + r][0] = part[r];
        __syncthreads();                                           // B7
        if (tid < MB)
            vsc_s[tid][v] = red_s[0][tid][0] + red_s[1][tid][0] +
                            red_s[2][tid][0] + red_s[3][tid][0] + P[P_VAB2];
    }

    // ---- combine: softmax over views * natt -> wt ----
    if (tid < MB) {
        float s0 = vsc_s[tid][0], s1 = vsc_s[tid][1], s2 = vsc_s[tid][2];
        float mx = fmaxf(s0, fmaxf(s1, s2));
        float e0 = __expf(s0 - mx), e1 = __expf(s1 - mx), e2 = __expf(s2 - mx);
        float inv = natt_s[tid] / (e0 + e1 + e2);
        aw_s[tid][0] = e0 * inv; aw_s[tid][1] = e1 * inv; aw_s[tid][2] = e2 * inv;
    }
    __syncthreads();                                               // B8
    u16* wt = zb[0];     // zb[0] (pe of v2) fully consumed before B7(v2)
    #pragma unroll
    for (int nt = 0; nt < 2; ++nt)
        #pragma unroll
        for (int r = 0; r < 4; ++r) {
            int row = q * 4 + r, col = nb + nt * 16 + i;
            float wv = aw_s[row][0] * viewr[0][nt][r] +
                       aw_s[row][1] * viewr[1][nt][r] +
                       aw_s[row][2] * viewr[2][nt][r];
            wt[row * LDA + col] = f2b(wv);
        }
    f32x4 accF[2] = {zz, zz};
    gemm128(xA, W1T, accF);
    __syncthreads();                                               // B9
    gemm128(wt, fus2T, accF);     // accF += wt @ fus_w[128:]
    float fR[2][4];
    #pragma unroll
    for (int nt = 0; nt < 2; ++nt)
        #pragma unroll
        for (int r = 0; r < 4; ++r) {
            int col = nb + nt * 16 + i;
            fR[nt][r] = fmaxf(accF[nt][r] + b1_s[col], 0.f);
        }
    f32x4 accT[2] = {zz, zz};
    gemm128(xA, ftT, accT);

    // ---- out = f + X@ft_w + ft_b, LayerNorm ----
    float ov[2][4], ps[4], pq[4];
    #pragma unroll
    for (int r = 0; r < 4; ++r) { ps[r] = 0.f; pq[r] = 0.f; }
    #pragma unroll
    for (int nt = 0; nt < 2; ++nt)
        #pragma unroll
        for (int r = 0; r < 4; ++r) {
            int col = nb + nt * 16 + i;
            float o = fR[nt][r] + accT[nt][r] + ftb_s[col];
            ov[nt][r] = o;
            ps[r] += o; pq[r] += o * o;
        }
    #pragma unroll
    for (int s = 1; s <= 8; s <<= 1)
        #pragma unroll
        for (int r = 0; r < 4; ++r) {
            ps[r] += __shfl_xor(ps[r], s);
            pq[r] += __shfl_xor(pq[r], s);
        }
    if (i == 0)
        #pragma unroll
        for (int r = 0; r < 4; ++r) {
            red_s[wid][q * 4 + r][0] = ps[r];
            red_s[wid][q * 4 + r][1] = pq[r];
        }
    __syncthreads();                                               // B10
    if (tid < MB) {
        float sm = red_s[0][tid][0] + red_s[1][tid][0] + red_s[2][tid][0] + red_s[3][tid][0];
        float sq = red_s[0][tid][1] + red_s[1][tid][1] + red_s[2][tid][1] + red_s[3][tid][1];
        float mu = sm * (1.f / 128.f);
        float var = sq * (1.f / 128.f) - mu * mu;
        mrs_s[tid][0] = mu; mrs_s[tid][1] = rsqrtf(var + 1e-5f);
    }
    __syncthreads();                                               // B11
    float* outf = (float*)zb;    // zb free: wt consumed before B10
    u16*   outb = (u16*)zb;
    #pragma unroll
    for (int nt = 0; nt < 2; ++nt)
        #pragma unroll
        for (int r = 0; r < 4; ++r) {
            int row = q * 4 + r, col = nb + nt * 16 + i;
            float val = (ov[nt][r] - mrs_s[row][0]) * mrs_s[row][1]
                        * lng_s[col] + lnb_s[col];
            if (f32) outf[row * 128 + col] = val;
            else     outb[row * 128 + col] = f2b(val);
        }
    __syncthreads();                                               // B12
    if (f32) {
        float* op = (float*)d_out + (size_t)nodebase * 128;
        for (int idx = tid; idx < 512; idx += 256)
            ((float4*)op)[idx] = ((const float4*)outf)[idx];
    } else {
        u16* op = (u16*)d_out + (size_t)nodebase * 128;
        ((uint4*)op)[tid] = ((const uint4*)outb)[tid];
    }
}

extern "C" void kernel_launch(void* const* d_in, const int* in_sizes, int n_in,
                              void* d_out, int out_size, void* d_ws, size_t ws_size,
                              hipStream_t stream) {
    const void* feat     = d_in[0];
    const int*  ei       = (const int*)d_in[1];
    const void* ew       = d_in[2];
    const void* rel_w    = d_in[3];
    const void* rel_b    = d_in[4];
    const void* gate_w   = d_in[5];
    const void* gate_b   = d_in[6];
    const void* la_w1    = d_in[7];
    const void* la_b1    = d_in[8];
    const void* la_w2    = d_in[9];
    const void* la_b2    = d_in[10];
    const void* pred_w   = d_in[11];
    const void* pred_b   = d_in[12];
    const void* att_bias = d_in[13];
    const void* view_pref= d_in[14];
    const void* va_w1    = d_in[15];
    const void* va_b1    = d_in[16];
    const void* va_w2    = d_in[17];
    const void* va_b2    = d_in[18];
    const void* ft_w     = d_in[19];
    const void* ft_b     = d_in[20];
    const void* sl_w     = d_in[21];
    const void* sl_b     = d_in[22];
    const void* fus_w    = d_in[23];
    const void* fus_b    = d_in[24];
    const void* ln_g     = d_in[25];
    const void* ln_beta  = d_in[26];

    // workspace layout (~38 MB total)
    int*   flag  = (int*)d_ws;                    // 4 ints
    int*   offs3 = flag + 4;                      // 3N
    int*   cur3  = offs3 + 3 * N_;                // 3N
    int2*  srcw3 = (int2*)(cur3 + 3 * N_);        // 3E int2 (16B-aligned)
    int*   bsum  = (int*)(srcw3 + 3 * E_);        // 3*128
    float* b1    = (float*)(bsum + 3 * 128);      // 128
    float* P     = b1 + 128;                      // 2182 (pad to 2304)
    u16*   W1T   = (u16*)(P + 2304);              // 16384
    u16*   relT  = W1T + 16384;                   // 3*16384
    u16*   gateT = relT + 3 * 16384;              // 3*16384
    u16*   vaT   = gateT + 3 * 16384;             // 8192
    u16*   fus2T = vaT + 8192;                    // 16384
    u16*   ftT   = fus2T + 16384;                 // 16384
    u16*   laT   = ftT + 16384;                   // 16384
    u16*   featB = laT + 16384;                   // N*128 bf16 (f32 input case)

    k_detect<<<1, 64, 0, stream>>>((const u16*)feat, flag);
    (void)hipMemsetAsync(cur3, 0, 3 * N_ * sizeof(int), stream);
    k_preC<<<PRE_TOT, 256, 0, stream>>>(flag, feat, featB,
                                        sl_w, sl_b, fus_w, fus_b, W1T, b1,
                                        rel_w, gate_w, va_w1, ft_w, la_w1,
                                        rel_b, gate_b, view_pref,
                                        va_b1, va_w2, va_b2,
                                        la_b1, la_w2, la_b2,
                                        pred_b, att_bias, ft_b, ln_g, ln_beta, pred_w,
                                        relT, gateT, vaT, fus2T, ftT, laT, P,
                                        ei, cur3);
    k_scan_bsum<<<3 * NB_SCAN, 256, 0, stream>>>(cur3, bsum);
    k_scan_write<<<3 * NB_SCAN, 256, 0, stream>>>(cur3, bsum, offs3);
    k_place<<<3 * EGRID, 256, 0, stream>>>(flag, ei, ew, cur3, srcw3);
    k_fused<<<NBLK, 256, 0, stream>>>(flag, feat, featB, srcw3, offs3, cur3,
                                      relT, gateT, vaT, W1T, fus2T, ftT, laT,
                                      b1, P, d_out);
}

// Round 5
// 544.174 us; speedup vs baseline: 1.2604x; 1.1466x over previous
//
#include <hip/hip_runtime.h>

#define N_ 100000
#define D_ 128
#define O_ 128
#define V_ 3
#define E_ 400000
#define NB_SCAN 98   // ceil(N/1024)
#define EGRID 1563   // ceil(E/256)
#define MB 32        // nodes per k_fused block
#define NBLK (N_ / MB)   // 3125
#define LDA 136      // padded bf16 row stride (16B-aligned)

// fused pre-kernel block ranges
#define PRE_CVT  6250                   // feature cvt (f32 path only)
#define PRE_PREW (PRE_CVT + 64)         // 6314
#define PRE_PREP (PRE_PREW + 617)       // 6931
#define PRE_TOT  (PRE_PREP + 3 * EGRID) // 11620

typedef unsigned short u16;
typedef __attribute__((ext_vector_type(8))) short bf16x8;   // 8 bf16 = 4 VGPRs
typedef __attribute__((ext_vector_type(4))) float f32x4;

#define MFMA16x16x32 __builtin_amdgcn_mfma_f32_16x16x32_bf16

// ---- fp32 param block offsets (in workspace, filled by prep) ----
#define P_RELB  0
#define P_GATEB 384
#define P_VP    768
#define P_VAB1  1152
#define P_VAW2  1216
#define P_VAB2  1280
#define P_LAB1  1281
#define P_LAW2  1409
#define P_LAB2  1537
#define P_PREDB 1539
#define P_ATTB  1541
#define P_FTB   1542
#define P_LNG   1670
#define P_LNB   1798
#define P_PREDW 1926
#define P_TOTAL 2182

__device__ __forceinline__ float b2f(u16 u) {
    union { float f; unsigned int i; } x; x.i = ((unsigned int)u) << 16; return x.f;
}
__device__ __forceinline__ float blo(unsigned int u) {
    union { float f; unsigned int i; } x; x.i = u << 16; return x.f;
}
__device__ __forceinline__ float bhi(unsigned int u) {
    union { float f; unsigned int i; } x; x.i = u & 0xffff0000u; return x.f;
}
__device__ __forceinline__ u16 f2b(float f) {
    union { float f; unsigned int i; } x; x.f = f;
    unsigned int r = x.i + 0x7FFFu + ((x.i >> 16) & 1u);
    return (u16)(r >> 16);
}

template<int F32> __device__ __forceinline__ float LD(const void* p, size_t i) {
    if (F32) return ((const float*)p)[i];
    return b2f(((const u16*)p)[i]);
}

// ---------------- dtype detector: fp32 vs bf16 element stream ----------------
__global__ void k_detect(const u16* __restrict__ feat, int* __restrict__ flag) {
    int t = threadIdx.x;   // 64 lanes; check feat[2i], i = t and t+64
    u16 a = feat[2 * t], b = feat[2 * t + 128];
    int zeros = (a == 0 ? 1 : 0) + (b == 0 ? 1 : 0);
    float va = b2f(a), vb = b2f(b);
    int bad = (!(va > -128.f && va < 128.f) ? 1 : 0) +
              (!(vb > -128.f && vb < 128.f) ? 1 : 0);
    #pragma unroll
    for (int s = 1; s <= 32; s <<= 1) {
        bad += __shfl_xor(bad, s);
        zeros += __shfl_xor(zeros, s);
    }
    if (t == 0) flag[0] = (bad >= 16 || zeros >= 64) ? 1 : 0;
}

// ---------------- fused pre kernel: cvt | prew | prep | count ----------------
__device__ __forceinline__ void cvt_body_f32(int b, const void* feat,
                                             u16* __restrict__ featB) {
    size_t idx = (size_t)b * 256 + threadIdx.x;   // 8 elems per thread
    const float4* fp = (const float4*)feat;
    float4 a = fp[idx * 2], c = fp[idx * 2 + 1];
    uint4 u;
    u.x = (unsigned)f2b(a.x) | ((unsigned)f2b(a.y) << 16);
    u.y = (unsigned)f2b(a.z) | ((unsigned)f2b(a.w) << 16);
    u.z = (unsigned)f2b(c.x) | ((unsigned)f2b(c.y) << 16);
    u.w = (unsigned)f2b(c.z) | ((unsigned)f2b(c.w) << 16);
    ((uint4*)featB)[idx] = u;
}

template<int F32>
__device__ __forceinline__ void prew_body(int b, const void* sl_w, const void* sl_b,
                                          const void* fus_w, const void* fus_b,
                                          u16* __restrict__ W1T, float* __restrict__ b1) {
    int gid = b * 256 + threadIdx.x;   // 64 blocks
    int d = gid >> 7, o = gid & 127;
    float acc = 0.f;
    for (int k = 0; k < 128; ++k)
        acc += LD<F32>(sl_w, d * 128 + k) * LD<F32>(fus_w, k * 128 + o);
    W1T[o * 128 + d] = f2b(acc);
    if (gid < 128) {
        float accb = 0.f;
        for (int k = 0; k < 128; ++k)
            accb += LD<F32>(sl_b, k) * LD<F32>(fus_w, k * 128 + gid);
        b1[gid] = accb + LD<F32>(fus_b, gid);
    }
}

template<int F32>
__device__ __forceinline__ void prep_body(int b,
        const void* rel_w, const void* gate_w, const void* va_w1, const void* fus_w,
        const void* ft_w, const void* la_w1,
        const void* rel_b, const void* gate_b, const void* vpref,
        const void* va_b1, const void* va_w2, const void* va_b2,
        const void* la_b1, const void* la_w2, const void* la_b2,
        const void* pred_b, const void* att_bias, const void* ft_b,
        const void* ln_g, const void* ln_beta, const void* pred_w,
        u16* __restrict__ relT, u16* __restrict__ gateT, u16* __restrict__ vaT,
        u16* __restrict__ fus2T, u16* __restrict__ ftT, u16* __restrict__ laT,
        float* __restrict__ P) {
    int id = b * 256 + threadIdx.x;
    if (id < 49152) {
        int v = id >> 14, r = id & 16383, o = r >> 7, d = r & 127;
        relT[id] = f2b(LD<F32>(rel_w, (size_t)v * 16384 + d * 128 + o));
    } else if (id < 98304) {
        int t = id - 49152, v = t >> 14, r = t & 16383, o = r >> 7, d = r & 127;
        gateT[t] = f2b(LD<F32>(gate_w, (size_t)v * 16384 + d * 128 + o));
    } else if (id < 106496) {
        int t = id - 98304, n = t >> 7, k = t & 127;
        vaT[t] = f2b(LD<F32>(va_w1, k * 64 + n));
    } else if (id < 122880) {
        int t = id - 106496, n = t >> 7, k = t & 127;
        fus2T[t] = f2b(LD<F32>(fus_w, (128 + k) * 128 + n));
    } else if (id < 139264) {
        int t = id - 122880, o = t >> 7, d = t & 127;
        ftT[t] = f2b(LD<F32>(ft_w, d * 128 + o));
    } else if (id < 155648) {
        int t = id - 139264, n = t >> 7, d = t & 127;
        int c = n >> 6, j = n & 63;
        laT[t] = f2b(LD<F32>(la_w1, c * 8192 + d * 64 + j));
    } else if (id < 155648 + P_TOTAL) {
        int t = id - 155648;
        float val;
        if      (t < P_GATEB) val = LD<F32>(rel_b, t);
        else if (t < P_VP)    val = LD<F32>(gate_b, t - P_GATEB);
        else if (t < P_VAB1)  val = LD<F32>(vpref, t - P_VP);
        else if (t < P_VAW2)  val = LD<F32>(va_b1, t - P_VAB1);
        else if (t < P_VAB2)  val = LD<F32>(va_w2, t - P_VAW2);
        else if (t < P_LAB1)  val = LD<F32>(va_b2, 0);
        else if (t < P_LAW2)  val = LD<F32>(la_b1, t - P_LAB1);
        else if (t < P_LAB2)  val = LD<F32>(la_w2, t - P_LAW2);
        else if (t < P_PREDB) val = LD<F32>(la_b2, t - P_LAB2);
        else if (t < P_ATTB)  val = LD<F32>(pred_b, t - P_PREDB);
        else if (t < P_FTB)   val = LD<F32>(att_bias, 0);
        else if (t < P_LNG)   val = LD<F32>(ft_b, t - P_FTB);
        else if (t < P_LNB)   val = LD<F32>(ln_g, t - P_LNG);
        else if (t < P_PREDW) val = LD<F32>(ln_beta, t - P_LNB);
        else                  val = LD<F32>(pred_w, t - P_PREDW);
        P[t] = val;
    }
}

__global__ __launch_bounds__(256) void k_preC(const int* __restrict__ flag,
        const void* feat, u16* __restrict__ featB,
        const void* sl_w, const void* sl_b, const void* fus_w, const void* fus_b,
        u16* __restrict__ W1T, float* __restrict__ b1,
        const void* rel_w, const void* gate_w, const void* va_w1,
        const void* ft_w, const void* la_w1,
        const void* rel_b, const void* gate_b, const void* vpref,
        const void* va_b1, const void* va_w2, const void* va_b2,
        const void* la_b1, const void* la_w2, const void* la_b2,
        const void* pred_b, const void* att_bias, const void* ft_b,
        const void* ln_g, const void* ln_beta, const void* pred_w,
        u16* __restrict__ relT, u16* __restrict__ gateT, u16* __restrict__ vaT,
        u16* __restrict__ fus2T, u16* __restrict__ ftT, u16* __restrict__ laT,
        float* __restrict__ P,
        const int* __restrict__ ei, int* __restrict__ cur3) {
    int b = blockIdx.x;
    if (b < PRE_CVT) {
        if (flag[0]) cvt_body_f32(b, feat, featB);   // bf16 case: featB unused
    } else if (b < PRE_PREW) {
        if (flag[0]) prew_body<1>(b - PRE_CVT, sl_w, sl_b, fus_w, fus_b, W1T, b1);
        else         prew_body<0>(b - PRE_CVT, sl_w, sl_b, fus_w, fus_b, W1T, b1);
    } else if (b < PRE_PREP) {
        if (flag[0]) prep_body<1>(b - PRE_PREW, rel_w, gate_w, va_w1, fus_w, ft_w, la_w1,
                                  rel_b, gate_b, vpref, va_b1, va_w2, va_b2,
                                  la_b1, la_w2, la_b2, pred_b, att_bias, ft_b,
                                  ln_g, ln_beta, pred_w, relT, gateT, vaT, fus2T, ftT, laT, P);
        else         prep_body<0>(b - PRE_PREW, rel_w, gate_w, va_w1, fus_w, ft_w, la_w1,
                                  rel_b, gate_b, vpref, va_b1, va_w2, va_b2,
                                  la_b1, la_w2, la_b2, pred_b, att_bias, ft_b,
                                  ln_g, ln_beta, pred_w, relT, gateT, vaT, fus2T, ftT, laT, P);
    } else {
        int b2 = b - PRE_PREP;
        int v = b2 / EGRID;
        int e = (b2 % EGRID) * 256 + threadIdx.x;
        if (e < E_) atomicAdd(&cur3[v * N_ + ei[(size_t)v * 2 * E_ + E_ + e]], 1);
    }
}

// ---------------- CSR scan: bsum / write (inline spine) ----------------------
__global__ __launch_bounds__(256) void k_scan_bsum(const int* __restrict__ cur3,
                                                   int* __restrict__ bsum) {
    __shared__ int red[256];
    const int v = blockIdx.x / NB_SCAN, b = blockIdx.x % NB_SCAN, tid = threadIdx.x;
    const int base = b * 1024;
    const int* counts = cur3 + v * N_;
    int s = 0;
    for (int i = tid; i < 1024; i += 256) {
        int idx = base + i;
        s += (idx < N_) ? counts[idx] : 0;
    }
    red[tid] = s;
    __syncthreads();
    for (int st = 128; st >= 1; st >>= 1) {
        if (tid < st) red[tid] += red[tid + st];
        __syncthreads();
    }
    if (tid == 0) bsum[v * 128 + b] = red[0];
}

__global__ __launch_bounds__(256) void k_scan_write(int* __restrict__ cur3,
                                                    const int* __restrict__ bsum,
                                                    int* __restrict__ offs3) {
    __shared__ int lsum[256];
    __shared__ int bs_s[128];
    const int v = blockIdx.x / NB_SCAN, b = blockIdx.x % NB_SCAN, tid = threadIdx.x;
    const int base = b * 1024;
    int* counts = cur3 + v * N_;
    int* offs   = offs3 + v * N_;
    if (tid < 128) bs_s[tid] = (tid < b) ? bsum[v * 128 + tid] : 0;
    int c[4]; int s = 0;
    #pragma unroll
    for (int k = 0; k < 4; ++k) {
        int idx = base + tid * 4 + k;
        c[k] = (idx < N_) ? counts[idx] : 0;
        s += c[k];
    }
    lsum[tid] = s;
    __syncthreads();
    for (int st = 1; st < 256; st <<= 1) {
        int t = (tid >= st) ? lsum[tid - st] : 0;
        __syncthreads();
        lsum[tid] += t;
        __syncthreads();
    }
    for (int st = 64; st >= 1; st >>= 1) {
        if (tid < st) bs_s[tid] += bs_s[tid + st];
        __syncthreads();
    }
    int off = bs_s[0] + lsum[tid] - s;
    #pragma unroll
    for (int k = 0; k < 4; ++k) {
        int idx = base + tid * 4 + k;
        if (idx < N_) { offs[idx] = off; counts[idx] = off; }
        off += c[k];
    }
}

// place: srcw[pos] = {src, weight-bits}
template<int F32>
__device__ __forceinline__ void place_body(const int* __restrict__ ei, const void* ew_all,
                                           int* __restrict__ cur3, int2* __restrict__ srcw3) {
    int v = blockIdx.x / EGRID;
    int e = (blockIdx.x % EGRID) * 256 + threadIdx.x;
    if (e < E_) {
        int dst = ei[(size_t)v * 2 * E_ + E_ + e];
        int src = ei[(size_t)v * 2 * E_ + e];
        float w = LD<F32>(ew_all, (size_t)v * E_ + e);
        int pos = atomicAdd(&cur3[v * N_ + dst], 1);
        int2 sw; sw.x = src; sw.y = __float_as_int(w);
        srcw3[(size_t)v * E_ + pos] = sw;
    }
    // afterwards cur3[v*N+n] == row end
}
__global__ __launch_bounds__(256) void k_place(const int* __restrict__ flag,
                                               const int* __restrict__ ei, const void* ew,
                                               int* __restrict__ cur3, int2* __restrict__ srcw3) {
    if (flag[0]) place_body<1>(ei, ew, cur3, srcw3);
    else         place_body<0>(ei, ew, cur3, srcw3);
}

// ------ fused MFMA pipeline: 768 threads, view-parallel wave groups ----------
// Group g (4 waves) owns view g's whole chain; 3 chains run concurrently.
// 12 barriers total (was ~22). LDS ~58 KB -> 2 blocks/CU = 24 waves (75%).
__global__ __launch_bounds__(768, 6) void k_fused(const int* __restrict__ flag,
        const void* feat, const u16* __restrict__ featB_,
        const int2* __restrict__ srcw3,
        const int* __restrict__ offs3, const int* __restrict__ ends3,
        const u16* __restrict__ relT, const u16* __restrict__ gateT,
        const u16* __restrict__ vaT, const u16* __restrict__ W1T,
        const u16* __restrict__ fus2T, const u16* __restrict__ ftT,
        const u16* __restrict__ laT,
        const float* __restrict__ b1, const float* __restrict__ P,
        void* __restrict__ d_out) {
    const int f32 = flag[0];
    const u16* __restrict__ fb = f32 ? featB_ : (const u16*)feat;

    __shared__ __align__(16) u16 xA[MB * LDA];        // features, bf16 A-layout
    __shared__ __align__(16) u16 zbuf[3][MB * LDA];   // per-view z/agg/vv; [0] later wt
    __shared__ __align__(16) float Fbuf[MB * 128];    // F2 exchange; out staging
    __shared__ float vp3_s[3][128];
    __shared__ float redL[4][MB];
    __shared__ float redv[3][4][MB];                  // va reduce; overlaid as LN red2
    __shared__ float wsn3[3][MB];
    __shared__ float aw_s[MB][3];
    __shared__ float natt_s[MB];
    __shared__ float lg_s[MB][2];
    __shared__ float mrs_s[MB][2];
    __shared__ float vab1_s[64], vaw2_s[64];
    __shared__ float predw_s[256];
    __shared__ float b1_s[128], ftb_s[128], lng_s[128], lnb_s[128];

    const int tid = threadIdx.x;
    const int g   = tid >> 8;               // wave-group / view 0..2
    const int t256 = tid & 255;
    const int wid = t256 >> 6;              // wave within group 0..3
    const int L = t256 & 63, q = L >> 4, i = L & 15;
    const int nb = wid * 32;
    const int nodebase = blockIdx.x * MB;
    const int nl = t256 >> 5, l32 = t256 & 31, o4 = l32 * 4;
    const int gsub = t256 >> 4, l16 = tid & 15, o8 = l16 * 8;
    const f32x4 zz = {0.f, 0.f, 0.f, 0.f};

    auto ldf = [&](const u16* B, int row, int k0) -> bf16x8 {
        return *(const bf16x8*)&B[row * LDA + k0];
    };
    auto ldg = [&](const u16* B, int row, int k0) -> bf16x8 {
        return *(const bf16x8*)&B[row * 128 + k0];
    };
    // M=32 gemm by the 4 waves of one group: acc[mt][nt]
    auto gemm32 = [&](const u16* A, const u16* Bg, f32x4 acc[2][2]) {
        #pragma unroll
        for (int kk = 0; kk < 4; ++kk) {
            int k0 = q * 8 + kk * 32;
            bf16x8 a0 = ldf(A, i, k0);
            bf16x8 a1 = ldf(A, i + 16, k0);
            bf16x8 bb0 = ldg(Bg, nb + i, k0);
            bf16x8 bb1 = ldg(Bg, nb + 16 + i, k0);
            acc[0][0] = MFMA16x16x32(a0, bb0, acc[0][0], 0, 0, 0);
            acc[0][1] = MFMA16x16x32(a0, bb1, acc[0][1], 0, 0, 0);
            acc[1][0] = MFMA16x16x32(a1, bb0, acc[1][0], 0, 0, 0);
            acc[1][1] = MFMA16x16x32(a1, bb1, acc[1][1], 0, 0, 0);
        }
    };
    // gather view g: 16 subgroups of 16 lanes; nodes gsub and gsub+16
    auto gather = [&]() {
        const int* offs = offs3 + g * N_;
        const int* ends = ends3 + g * N_;
        const int2* srcw = srcw3 + (size_t)g * E_;
        #pragma unroll
        for (int rep = 0; rep < 2; ++rep) {
            const int m = gsub + rep * 16;
            const int node = nodebase + m;
            float z0 = 0.f, z1 = 0.f, z2 = 0.f, z3 = 0.f;
            float z4 = 0.f, z5 = 0.f, z6 = 0.f, z7 = 0.f, ws = 0.f;
            int j = offs[node], jend = ends[node];
            while (j < jend) {
                int r = jend - j;
                int2 e0 = srcw[j];
                int2 e1, e2, e3;
                e1.x = 0; e1.y = 0; e2.x = 0; e2.y = 0; e3.x = 0; e3.y = 0;
                if (r > 1) e1 = srcw[j + 1];
                if (r > 2) e2 = srcw[j + 2];
                if (r > 3) e3 = srcw[j + 3];
                uint4 x0, x1, x2, x3;
                x1.x = x1.y = x1.z = x1.w = 0;
                x2.x = x2.y = x2.z = x2.w = 0;
                x3.x = x3.y = x3.z = x3.w = 0;
                x0 = *(const uint4*)&fb[(size_t)e0.x * 128 + o8];
                if (r > 1) x1 = *(const uint4*)&fb[(size_t)e1.x * 128 + o8];
                if (r > 2) x2 = *(const uint4*)&fb[(size_t)e2.x * 128 + o8];
                if (r > 3) x3 = *(const uint4*)&fb[(size_t)e3.x * 128 + o8];
                float w0 = __int_as_float(e0.y), w1 = __int_as_float(e1.y);
                float w2 = __int_as_float(e2.y), w3 = __int_as_float(e3.y);
                ws += w0 + w1 + w2 + w3;
                z0 += w0 * blo(x0.x) + w1 * blo(x1.x) + w2 * blo(x2.x) + w3 * blo(x3.x);
                z1 += w0 * bhi(x0.x) + w1 * bhi(x1.x) + w2 * bhi(x2.x) + w3 * bhi(x3.x);
                z2 += w0 * blo(x0.y) + w1 * blo(x1.y) + w2 * blo(x2.y) + w3 * blo(x3.y);
                z3 += w0 * bhi(x0.y) + w1 * bhi(x1.y) + w2 * bhi(x2.y) + w3 * bhi(x3.y);
                z4 += w0 * blo(x0.z) + w1 * blo(x1.z) + w2 * blo(x2.z) + w3 * blo(x3.z);
                z5 += w0 * bhi(x0.z) + w1 * bhi(x1.z) + w2 * bhi(x2.z) + w3 * bhi(x3.z);
                z6 += w0 * blo(x0.w) + w1 * blo(x1.w) + w2 * blo(x2.w) + w3 * blo(x3.w);
                z7 += w0 * bhi(x0.w) + w1 * bhi(x1.w) + w2 * bhi(x2.w) + w3 * bhi(x3.w);
                j += 4;
            }
            uint4 u;
            u.x = (unsigned)f2b(z0) | ((unsigned)f2b(z1) << 16);
            u.y = (unsigned)f2b(z2) | ((unsigned)f2b(z3) << 16);
            u.z = (unsigned)f2b(z4) | ((unsigned)f2b(z5) << 16);
            u.w = (unsigned)f2b(z6) | ((unsigned)f2b(z7) << 16);
            *(uint4*)&zbuf[g][m * LDA + o8] = u;
            if (l16 == 0) wsn3[g][m] = ws;
        }
    };

    // ---- P0: stage xA + consts; each group gathers its view ----
    if (tid < 512) {
        int m = tid >> 4, s = tid & 15;
        *(uint4*)&xA[m * LDA + s * 8] =
            *(const uint4*)&fb[(size_t)(nodebase + m) * 128 + s * 8];
    }
    if (tid < 64) { vab1_s[tid] = P[P_VAB1 + tid]; vaw2_s[tid] = P[P_VAW2 + tid]; }
    if (tid < 128) {
        b1_s[tid]  = b1[tid];
        ftb_s[tid] = P[P_FTB + tid];
        lng_s[tid] = P[P_LNG + tid];
        lnb_s[tid] = P[P_LNB + tid];
    }
    if (tid < 256) predw_s[tid] = P[P_PREDW + tid];
    if (tid >= 256 && tid < 640) {  // vp3: 384 floats
        int t = tid - 256;
        vp3_s[t >> 7][t & 127] = P[P_VP + t];
    }
    gather();
    __syncthreads();                                               // B1

    // ---- P1: rel gemms (all groups) + label-attention (group 0 extra) ----
    f32x4 accA[2][2] = {{zz, zz}, {zz, zz}};
    gemm32(zbuf[g], relT + (size_t)g * 16384, accA);
    if (g == 0) {
        f32x4 accL[2][2] = {{zz, zz}, {zz, zz}};
        gemm32(xA, laT, accL);
        #pragma unroll
        for (int rep = 0; rep < 4; ++rep) {
            int m = rep * 8 + nl;
            float lg0 = 0.f, lg1 = 0.f;
            #pragma unroll
            for (int t = 0; t < 4; ++t) {
                float xv = b2f(xA[m * LDA + o4 + t]);
                lg0 += xv * predw_s[(o4 + t) * 2 + 0];
                lg1 += xv * predw_s[(o4 + t) * 2 + 1];
            }
            #pragma unroll
            for (int s = 1; s <= 16; s <<= 1) {
                lg0 += __shfl_xor(lg0, s);
                lg1 += __shfl_xor(lg1, s);
            }
            if (l32 == 0) { lg_s[m][0] = lg0; lg_s[m][1] = lg1; }
        }
        float la0 = P[P_LAB1 + nb + i],  la1 = P[P_LAB1 + nb + 16 + i];
        float lw0 = P[P_LAW2 + nb + i],  lw1 = P[P_LAW2 + nb + 16 + i];
        float partL[2][4];
        #pragma unroll
        for (int mt = 0; mt < 2; ++mt)
            #pragma unroll
            for (int r = 0; r < 4; ++r) {
                float h0 = fmaxf(accL[mt][0][r] + la0, 0.f);
                float h1 = fmaxf(accL[mt][1][r] + la1, 0.f);
                partL[mt][r] = h0 * lw0 + h1 * lw1;
            }
        #pragma unroll
        for (int s = 1; s <= 8; s <<= 1)
            #pragma unroll
            for (int mt = 0; mt < 2; ++mt)
                #pragma unroll
                for (int r = 0; r < 4; ++r)
                    partL[mt][r] += __shfl_xor(partL[mt][r], s);
        if (i == 0)
            #pragma unroll
            for (int mt = 0; mt < 2; ++mt)
                #pragma unroll
                for (int r = 0; r < 4; ++r)
                    redL[wid][mt * 16 + q * 4 + r] = partL[mt][r];
    }
    __syncthreads();                                               // B2

    // ---- P2: agg = acc + wsn*rel_b -> zbuf[g]; natt (tid<32) ----
    {
        float rb0 = P[P_RELB + g * 128 + nb + i];
        float rb1 = P[P_RELB + g * 128 + nb + 16 + i];
        #pragma unroll
        for (int mt = 0; mt < 2; ++mt)
            #pragma unroll
            for (int nt = 0; nt < 2; ++nt) {
                float rb = nt ? rb1 : rb0;
                int col = nb + nt * 16 + i;
                #pragma unroll
                for (int r = 0; r < 4; ++r) {
                    int row = mt * 16 + q * 4 + r;
                    float a = accA[mt][nt][r] + wsn3[g][row] * rb;
                    accA[mt][nt][r] = a;
                    zbuf[g][row * LDA + col] = f2b(a);
                }
            }
    }
    if (tid < MB) {
        float c0 = redL[0][tid] + redL[1][tid] + P[P_LAB2 + 0];
        float c1 = redL[2][tid] + redL[3][tid] + P[P_LAB2 + 1];
        float s0 = 1.f / (1.f + __expf(-c0));
        float s1 = 1.f / (1.f + __expf(-c1));
        float l0 = lg_s[tid][0] + P[P_PREDB + 0];
        float l1 = lg_s[tid][1] + P[P_PREDB + 1];
        float mx = fmaxf(l0, l1);
        float e0 = __expf(l0 - mx), e1 = __expf(l1 - mx);
        float inv = 1.f / (e0 + e1);
        float p0 = e0 * inv, p1 = e1 * inv;
        natt_s[tid] = s0 * p0 + s1 * p1 + P[P_ATTB];
        int node = nodebase + tid;
        if (f32) {
            float* pr = (float*)d_out + (size_t)N_ * O_;
            pr[node * 2 + 0] = p0; pr[node * 2 + 1] = p1;
        } else {
            u16* pr = (u16*)d_out + (size_t)N_ * O_;
            pr[node * 2 + 0] = f2b(p0); pr[node * 2 + 1] = f2b(p1);
        }
    }
    __syncthreads();                                               // B3

    // ---- P3: gate gemm ----
    f32x4 acc2[2][2] = {{zz, zz}, {zz, zz}};
    gemm32(zbuf[g], gateT + (size_t)g * 16384, acc2);
    __syncthreads();                                               // B4

    // ---- P4: vv = sigmoid(acc2+gb)*agg -> zbuf[g] ----
    {
        float gb0 = P[P_GATEB + g * 128 + nb + i];
        float gb1 = P[P_GATEB + g * 128 + nb + 16 + i];
        #pragma unroll
        for (int mt = 0; mt < 2; ++mt)
            #pragma unroll
            for (int nt = 0; nt < 2; ++nt) {
                float gb = nt ? gb1 : gb0;
                int col = nb + nt * 16 + i;
                #pragma unroll
                for (int r = 0; r < 4; ++r) {
                    int row = mt * 16 + q * 4 + r;
                    float gt = 1.f / (1.f + __expf(-(acc2[mt][nt][r] + gb)));
                    zbuf[g][row * LDA + col] = f2b(gt * accA[mt][nt][r]);
                }
            }
    }
    __syncthreads();                                               // B5

    // ---- P5: va gemm on pe = vv*vp (vp folded into A-frag) ----
    {
        f32x4 accV[2] = {zz, zz};
        const int nbv = wid * 16, colv = nbv + i;
        #pragma unroll
        for (int kk = 0; kk < 4; ++kk) {
            int k0 = q * 8 + kk * 32;
            bf16x8 a0r = ldf(zbuf[g], i, k0);
            bf16x8 a1r = ldf(zbuf[g], i + 16, k0);
            bf16x8 a0, a1;
            #pragma unroll
            for (int e = 0; e < 8; ++e) {
                float vp = vp3_s[g][k0 + e];
                a0[e] = (short)f2b(b2f((u16)a0r[e]) * vp);
                a1[e] = (short)f2b(b2f((u16)a1r[e]) * vp);
            }
            bf16x8 bb = ldg(vaT, nbv + i, k0);
            accV[0] = MFMA16x16x32(a0, bb, accV[0], 0, 0, 0);
            accV[1] = MFMA16x16x32(a1, bb, accV[1], 0, 0, 0);
        }
        float part[2][4];
        #pragma unroll
        for (int mt = 0; mt < 2; ++mt)
            #pragma unroll
            for (int r = 0; r < 4; ++r) {
                float vh = fmaxf(accV[mt][r] + vab1_s[colv], 0.f);
                part[mt][r] = vh * vaw2_s[colv];
            }
        #pragma unroll
        for (int s = 1; s <= 8; s <<= 1)
            #pragma unroll
            for (int mt = 0; mt < 2; ++mt)
                #pragma unroll
                for (int r = 0; r < 4; ++r)
                    part[mt][r] += __shfl_xor(part[mt][r], s);
        if (i == 0)
            #pragma unroll
            for (int mt = 0; mt < 2; ++mt)
                #pragma unroll
                for (int r = 0; r < 4; ++r)
                    redv[g][wid][mt * 16 + q * 4 + r] = part[mt][r];
    }
    __syncthreads();                                               // B6

    // ---- P6: vscore + view softmax * natt (tid<32) ----
    if (tid < MB) {
        float sv[3];
        #pragma unroll
        for (int v = 0; v < 3; ++v)
            sv[v] = redv[v][0][tid] + redv[v][1][tid] +
                    redv[v][2][tid] + redv[v][3][tid] + P[P_VAB2];
        float mx = fmaxf(sv[0], fmaxf(sv[1], sv[2]));
        float e0 = __expf(sv[0] - mx), e1 = __expf(sv[1] - mx), e2 = __expf(sv[2] - mx);
        float inv = natt_s[tid] / (e0 + e1 + e2);
        aw_s[tid][0] = e0 * inv; aw_s[tid][1] = e1 * inv; aw_s[tid][2] = e2 * inv;
    }
    __syncthreads();                                               // B7

    // ---- P7: combine wt = sum_v aw_v*vv_v -> zbuf[0] (in place, lane-owned) --
    for (int idx = tid; idx < MB * 128; idx += 768) {
        int row = idx >> 7, col = idx & 127;
        float w = aw_s[row][0] * b2f(zbuf[0][row * LDA + col]) +
                  aw_s[row][1] * b2f(zbuf[1][row * LDA + col]) +
                  aw_s[row][2] * b2f(zbuf[2][row * LDA + col]);
        zbuf[0][row * LDA + col] = f2b(w);
    }
    __syncthreads();                                               // B8

    // ---- P8: fusion gemms, one per group ----
    float* F1 = (float*)&zbuf[1][0];    // 16 KB overlay on zbuf[1..2] (free)
    f32x4 accG[2][2] = {{zz, zz}, {zz, zz}};
    if (g == 0) {
        gemm32(xA, W1T, accG);
        #pragma unroll
        for (int mt = 0; mt < 2; ++mt)
            #pragma unroll
            for (int nt = 0; nt < 2; ++nt)
                #pragma unroll
                for (int r = 0; r < 4; ++r)
                    F1[(mt * 16 + q * 4 + r) * 128 + nb + nt * 16 + i] = accG[mt][nt][r];
    } else if (g == 1) {
        gemm32(zbuf[0], fus2T, accG);
        #pragma unroll
        for (int mt = 0; mt < 2; ++mt)
            #pragma unroll
            for (int nt = 0; nt < 2; ++nt)
                #pragma unroll
                for (int r = 0; r < 4; ++r)
                    Fbuf[(mt * 16 + q * 4 + r) * 128 + nb + nt * 16 + i] = accG[mt][nt][r];
    } else {
        gemm32(xA, ftT, accG);          // accT kept in regs
    }
    __syncthreads();                                               // B9

    // ---- P9: group 2: out = relu(F1+F2+b1) + accT + ftb; LN partials ----
    float ov[2][2][4];
    if (g == 2) {
        float ps[2][4], pq[2][4];
        #pragma unroll
        for (int mt = 0; mt < 2; ++mt)
            #pragma unroll
            for (int r = 0; r < 4; ++r) { ps[mt][r] = 0.f; pq[mt][r] = 0.f; }
        #pragma unroll
        for (int mt = 0; mt < 2; ++mt)
            #pragma unroll
            for (int nt = 0; nt < 2; ++nt)
                #pragma unroll
                for (int r = 0; r < 4; ++r) {
                    int row = mt * 16 + q * 4 + r, col = nb + nt * 16 + i;
                    float o = fmaxf(F1[row * 128 + col] + Fbuf[row * 128 + col]
                                    + b1_s[col], 0.f)
                              + accG[mt][nt][r] + ftb_s[col];
                    ov[mt][nt][r] = o;
                    ps[mt][r] += o; pq[mt][r] += o * o;
                }
        #pragma unroll
        for (int s = 1; s <= 8; s <<= 1)
            #pragma unroll
            for (int mt = 0; mt < 2; ++mt)
                #pragma unroll
                for (int r = 0; r < 4; ++r) {
                    ps[mt][r] += __shfl_xor(ps[mt][r], s);
                    pq[mt][r] += __shfl_xor(pq[mt][r], s);
                }
        float* red2 = &redv[0][0][0];    // overlay: [wid][row][2], 256 floats
        if (i == 0)
            #pragma unroll
            for (int mt = 0; mt < 2; ++mt)
                #pragma unroll
                for (int r = 0; r < 4; ++r) {
                    int row = mt * 16 + q * 4 + r;
                    red2[wid * 64 + row * 2 + 0] = ps[mt][r];
                    red2[wid * 64 + row * 2 + 1] = pq[mt][r];
                }
    }
    __syncthreads();                                               // B10

    // ---- P10: LN stats (tid<32) ----
    if (tid < MB) {
        const float* red2 = &redv[0][0][0];
        float sm = red2[tid * 2] + red2[64 + tid * 2] +
                   red2[128 + tid * 2] + red2[192 + tid * 2];
        float sq = red2[tid * 2 + 1] + red2[64 + tid * 2 + 1] +
                   red2[128 + tid * 2 + 1] + red2[192 + tid * 2 + 1];
        float mu = sm * (1.f / 128.f);
        float var = sq * (1.f / 128.f) - mu * mu;
        mrs_s[tid][0] = mu; mrs_s[tid][1] = rsqrtf(var + 1e-5f);
    }
    __syncthreads();                                               // B11

    // ---- P11: group 2 writes normalized out to staging (Fbuf) ----
    if (g == 2) {
        #pragma unroll
        for (int mt = 0; mt < 2; ++mt)
            #pragma unroll
            for (int nt = 0; nt < 2; ++nt)
                #pragma unroll
                for (int r = 0; r < 4; ++r) {
                    int row = mt * 16 + q * 4 + r, col = nb + nt * 16 + i;
                    float val = (ov[mt][nt][r] - mrs_s[row][0]) * mrs_s[row][1]
                                * lng_s[col] + lnb_s[col];
                    if (f32) Fbuf[row * 128 + col] = val;
                    else     ((u16*)Fbuf)[row * 128 + col] = f2b(val);
                }
    }
    __syncthreads();                                               // B12

    // ---- P12: coalesced store ----
    if (f32) {
        float* op = (float*)d_out + (size_t)nodebase * 128;
        for (int idx = tid; idx < 1024; idx += 768)
            ((float4*)op)[idx] = ((const float4*)Fbuf)[idx];
    } else {
        u16* op = (u16*)d_out + (size_t)nodebase * 128;
        if (tid < 512)
            ((uint4*)op)[tid] = ((const uint4*)Fbuf)[tid];
    }
}

extern "C" void kernel_launch(void* const* d_in, const int* in_sizes, int n_in,
                              void* d_out, int out_size, void* d_ws, size_t ws_size,
                              hipStream_t stream) {
    const void* feat     = d_in[0];
    const int*  ei       = (const int*)d_in[1];
    const void* ew       = d_in[2];
    const void* rel_w    = d_in[3];
    const void* rel_b    = d_in[4];
    const void* gate_w   = d_in[5];
    const void* gate_b   = d_in[6];
    const void* la_w1    = d_in[7];
    const void* la_b1    = d_in[8];
    const void* la_w2    = d_in[9];
    const void* la_b2    = d_in[10];
    const void* pred_w   = d_in[11];
    const void* pred_b   = d_in[12];
    const void* att_bias = d_in[13];
    const void* view_pref= d_in[14];
    const void* va_w1    = d_in[15];
    const void* va_b1    = d_in[16];
    const void* va_w2    = d_in[17];
    const void* va_b2    = d_in[18];
    const void* ft_w     = d_in[19];
    const void* ft_b     = d_in[20];
    const void* sl_w     = d_in[21];
    const void* sl_b     = d_in[22];
    const void* fus_w    = d_in[23];
    const void* fus_b    = d_in[24];
    const void* ln_g     = d_in[25];
    const void* ln_beta  = d_in[26];

    // workspace layout (~38 MB total)
    int*   flag  = (int*)d_ws;                    // 4 ints
    int*   offs3 = flag + 4;                      // 3N
    int*   cur3  = offs3 + 3 * N_;                // 3N
    int2*  srcw3 = (int2*)(cur3 + 3 * N_);        // 3E int2 (16B-aligned)
    int*   bsum  = (int*)(srcw3 + 3 * E_);        // 3*128
    float* b1    = (float*)(bsum + 3 * 128);      // 128
    float* P     = b1 + 128;                      // 2182 (pad to 2304)
    u16*   W1T   = (u16*)(P + 2304);              // 16384
    u16*   relT  = W1T + 16384;                   // 3*16384
    u16*   gateT = relT + 3 * 16384;              // 3*16384
    u16*   vaT   = gateT + 3 * 16384;             // 8192
    u16*   fus2T = vaT + 8192;                    // 16384
    u16*   ftT   = fus2T + 16384;                 // 16384
    u16*   laT   = ftT + 16384;                   // 16384
    u16*   featB = laT + 16384;                   // N*128 bf16 (f32 input case)

    k_detect<<<1, 64, 0, stream>>>((const u16*)feat, flag);
    (void)hipMemsetAsync(cur3, 0, 3 * N_ * sizeof(int), stream);
    k_preC<<<PRE_TOT, 256, 0, stream>>>(flag, feat, featB,
                                        sl_w, sl_b, fus_w, fus_b, W1T, b1,
                                        rel_w, gate_w, va_w1, ft_w, la_w1,
                                        rel_b, gate_b, view_pref,
                                        va_b1, va_w2, va_b2,
                                        la_b1, la_w2, la_b2,
                                        pred_b, att_bias, ft_b, ln_g, ln_beta, pred_w,
                                        relT, gateT, vaT, fus2T, ftT, laT, P,
                                        ei, cur3);
    k_scan_bsum<<<3 * NB_SCAN, 256, 0, stream>>>(cur3, bsum);
    k_scan_write<<<3 * NB_SCAN, 256, 0, stream>>>(cur3, bsum, offs3);
    k_place<<<3 * EGRID, 256, 0, stream>>>(flag, ei, ew, cur3, srcw3);
    k_fused<<<NBLK, 768, 0, stream>>>(flag, feat, featB, srcw3, offs3, cur3,
                                      relT, gateT, vaT, W1T, fus2T, ftT, laT,
                                      b1, P, d_out);
}